// Round 8
// baseline (358.946 us; speedup 1.0000x reference)
//
#include <hip/hip_runtime.h>
#include <math.h>

// Shapes (fixed)
#define B_ 4
#define S_ 256
#define N_ 32
#define H_ 256
#define NH_ 8
#define HD_ 32
#define FF_ 512
#define BN_ 128
#define M_ 32768   // BN_*S_
#define BS_ 1024   // B_*S_

typedef __attribute__((ext_vector_type(8))) short short8;
typedef __attribute__((ext_vector_type(4))) short short4v;
typedef __attribute__((ext_vector_type(4))) float f32x4;
typedef __attribute__((ext_vector_type(16))) float f32x16;
typedef __attribute__((ext_vector_type(4))) int i32x4;

__device__ __forceinline__ unsigned short f2bf(float f) {
  unsigned u = __builtin_bit_cast(unsigned, f);
  u = (u + 0x7FFFu + ((u >> 16) & 1u)) >> 16;
  return (unsigned short)u;
}
__device__ __forceinline__ float bf2f(unsigned short h) {
  unsigned u = ((unsigned)h) << 16;
  return __builtin_bit_cast(float, u);
}

// ---------------------------------------------------------------------------
// time_state[bs, h] (fp32)
// ---------------------------------------------------------------------------
__global__ __launch_bounds__(256)
void ts_kernel(const float* __restrict__ reg, const float* __restrict__ tr,
               const int* __restrict__ codes,
               const float* __restrict__ sess_emb,
               const float* __restrict__ reg_w, const float* __restrict__ reg_b,
               const float* __restrict__ tr_w, const float* __restrict__ tr_b,
               float* __restrict__ ts) {
  const int bs = blockIdx.x;
  const int h = threadIdx.x;
  int c = codes[bs];
  c = c < 0 ? 0 : (c > 7 ? 7 : c);
  const float r = reg[bs], t = tr[bs];
  ts[bs * H_ + h] = sess_emb[c * H_ + h] + r * reg_w[h] + reg_b[h]
                    + t * tr_w[h] + tr_b[h];
}

// ---------------------------------------------------------------------------
// All weight conversions in one launch. W[K][N] fp32 -> Wt[N][K] bf16.
// ---------------------------------------------------------------------------
__global__ __launch_bounds__(256)
void cvtall_kernel(const float* __restrict__ q_w, const float* __restrict__ k_w,
                   const float* __restrict__ v_w, const float* __restrict__ o_w,
                   const float* __restrict__ tq_w, const float* __restrict__ tk_w,
                   const float* __restrict__ ff1_w, const float* __restrict__ ff2_w,
                   unsigned short* __restrict__ wqk, unsigned short* __restrict__ wv,
                   unsigned short* __restrict__ wo, unsigned short* __restrict__ wtqtk,
                   unsigned short* __restrict__ wff1, unsigned short* __restrict__ wff2) {
  const int bid = blockIdx.x, tid = threadIdx.x;
  const float* src; unsigned short* dst; int ns, K, base;
  if (bid < 256)       { src = q_w;   dst = wqk;           ns = 8; K = 256; base = 0; }
  else if (bid < 512)  { src = k_w;   dst = wqk + 65536;   ns = 8; K = 256; base = 256; }
  else if (bid < 768)  { src = v_w;   dst = wv;            ns = 8; K = 256; base = 512; }
  else if (bid < 1024) { src = o_w;   dst = wo;            ns = 8; K = 256; base = 768; }
  else if (bid < 1280) { src = tq_w;  dst = wtqtk;         ns = 8; K = 256; base = 1024; }
  else if (bid < 1536) { src = tk_w;  dst = wtqtk + 65536; ns = 8; K = 256; base = 1280; }
  else if (bid < 2048) { src = ff1_w; dst = wff1;          ns = 9; K = 256; base = 1536; }
  else                 { src = ff2_w; dst = wff2;          ns = 8; K = 512; base = 2048; }
  const int idx = (bid - base) * 256 + tid;
  const int k = idx >> ns, n = idx & ((1 << ns) - 1);
  dst[n * K + k] = f2bf(src[idx]);
}

// ---------------------------------------------------------------------------
// Prep: flatb = bf16(seq gathered to [M,256]); fpb = bf16(seq + ts).
// ---------------------------------------------------------------------------
__global__ __launch_bounds__(256)
void prep_kernel(const float* __restrict__ seq, const float* __restrict__ ts,
                 unsigned short* __restrict__ flatb, unsigned short* __restrict__ fpb) {
  const int row = blockIdx.x * 8 + (threadIdx.x >> 5);
  const int c0 = (threadIdx.x & 31) * 8;
  const int bn = row >> 8, s = row & 255;
  const int b = bn >> 5, n = bn & 31;
  const float* sp = &seq[((((b << 8) + s) << 5) + n) * 256 + c0];
  const float* tp = &ts[(((b << 8) + s) << 8) + c0];
  const float4 a0 = *(const float4*)sp, a1 = *(const float4*)(sp + 4);
  const float4 t0 = *(const float4*)tp, t1 = *(const float4*)(tp + 4);
  short8 fv, gv;
  fv[0] = (short)f2bf(a0.x); fv[1] = (short)f2bf(a0.y);
  fv[2] = (short)f2bf(a0.z); fv[3] = (short)f2bf(a0.w);
  fv[4] = (short)f2bf(a1.x); fv[5] = (short)f2bf(a1.y);
  fv[6] = (short)f2bf(a1.z); fv[7] = (short)f2bf(a1.w);
  gv[0] = (short)f2bf(a0.x + t0.x); gv[1] = (short)f2bf(a0.y + t0.y);
  gv[2] = (short)f2bf(a0.z + t0.z); gv[3] = (short)f2bf(a0.w + t0.w);
  gv[4] = (short)f2bf(a1.x + t1.x); gv[5] = (short)f2bf(a1.y + t1.y);
  gv[6] = (short)f2bf(a1.z + t1.z); gv[7] = (short)f2bf(a1.w + t1.w);
  *(short8*)&flatb[row * 256 + c0] = fv;
  *(short8*)&fpb[row * 256 + c0] = gv;
}

// ---------------------------------------------------------------------------
// bf16 MFMA GEMM: C[M,NOUT] = epilogue(A @ W + bias)
// AMODE: 0 = fp32 A[M,K]; 3 = bf16 A[M,K]
// RESMODE: 0 none; 2 + resb (bf16 [M,NOUT])
// DUALB: bias for col<256, bias2 for col>=256. SCALEH: post_scale only col<256.
// ---------------------------------------------------------------------------
template<int AMODE, int RESMODE, bool GELU_, int K, int NOUT, bool OUTBF,
         bool DUALB, bool SCALEH>
__global__ __launch_bounds__(256)
void mmb_kernel(const void* __restrict__ Av, const unsigned short* __restrict__ Wt,
                const float* __restrict__ bias, const float* __restrict__ bias2,
                const unsigned short* __restrict__ resb,
                void* __restrict__ Cv, float post_scale) {
  __shared__ unsigned short As[128][72];
  __shared__ unsigned short Bs[128][72];
  const int tid = threadIdx.x;
  const int m0 = blockIdx.x * 128, n0 = blockIdx.y * 128;
  const int l = tid & 63, w = tid >> 6;
  const int wr = w >> 1, wc = w & 1;
  const int lr = l & 15, lg = l >> 4;
  f32x4 acc[4][4] = {};

  for (int k0 = 0; k0 < K; k0 += 64) {
    if (AMODE == 3) {
      const unsigned short* Ab = (const unsigned short*)Av;
#pragma unroll
      for (int i = 0; i < 4; ++i) {
        const int seg = i * 256 + tid;
        const int r = seg >> 3, c8 = (seg & 7) * 8;
        const short8 v = *(const short8*)&Ab[(m0 + r) * K + k0 + c8];
        *(short8*)&As[r][c8] = v;
      }
    } else {
#pragma unroll
      for (int i = 0; i < 8; ++i) {
        const int seg = i * 256 + tid;
        const int r = seg >> 4, c4 = (seg & 15) * 4;
        const float4 a4 = *(const float4*)&((const float*)Av)[(m0 + r) * K + k0 + c4];
        short4v sv;
        sv[0] = (short)f2bf(a4.x); sv[1] = (short)f2bf(a4.y);
        sv[2] = (short)f2bf(a4.z); sv[3] = (short)f2bf(a4.w);
        *(short4v*)&As[r][c4] = sv;
      }
    }
#pragma unroll
    for (int i = 0; i < 4; ++i) {
      const int seg = i * 256 + tid;
      const int n = seg >> 3, c8 = (seg & 7) * 8;
      const short8 v = *(const short8*)&Wt[(n0 + n) * K + k0 + c8];
      *(short8*)&Bs[n][c8] = v;
    }
    __syncthreads();
#pragma unroll
    for (int ks = 0; ks < 2; ++ks) {
      short8 af[4], bfr[4];
#pragma unroll
      for (int qt = 0; qt < 4; ++qt)
        af[qt] = *(const short8*)&As[wr * 64 + qt * 16 + lr][ks * 32 + lg * 8];
#pragma unroll
      for (int nt = 0; nt < 4; ++nt)
        bfr[nt] = *(const short8*)&Bs[wc * 64 + nt * 16 + lr][ks * 32 + lg * 8];
#pragma unroll
      for (int qt = 0; qt < 4; ++qt)
#pragma unroll
        for (int nt = 0; nt < 4; ++nt)
          acc[qt][nt] = __builtin_amdgcn_mfma_f32_16x16x32_bf16(
              af[qt], bfr[nt], acc[qt][nt], 0, 0, 0);
    }
    __syncthreads();
  }

#pragma unroll
  for (int qt = 0; qt < 4; ++qt) {
#pragma unroll
    for (int nt = 0; nt < 4; ++nt) {
      const int col = n0 + wc * 64 + nt * 16 + lr;
      const float bsv = DUALB ? (col < 256 ? bias[col] : bias2[col - 256])
                              : bias[col];
      const float sc = SCALEH ? (col < 256 ? post_scale : 1.0f) : post_scale;
#pragma unroll
      for (int i = 0; i < 4; ++i) {
        const int row = m0 + wr * 64 + qt * 16 + (lg << 2) + i;
        float v = (acc[qt][nt][i] + bsv) * sc;
        if (RESMODE == 2) v += bf2f(resb[row * NOUT + col]);
        if (GELU_) v = 0.5f * v * (1.0f + erff(v * 0.70710678118654752f));
        if (OUTBF) ((unsigned short*)Cv)[row * NOUT + col] = f2bf(v);
        else       ((float*)Cv)[row * NOUT + col] = v;
      }
    }
  }
}

// ---------------------------------------------------------------------------
// Attention v6: split-key wave pairs (enabled by no-max softmax).
// 1024 thr = 16 waves. Pair p = w>>1 owns query chunk p; parity e = w&1
// handles key groups g == e (mod 2), g <= p  ->  max 4 serial groups/wave.
// Partials combine by pure addition (no rescale). Merge via LDS aliased
// over KsB (dead after compute), [r][lane] layout = conflict-free.
// ---------------------------------------------------------------------------
__global__ __launch_bounds__(1024, 8)
void attn5_kernel(const unsigned short* __restrict__ qkb,   // [M][512] q|k
                  const unsigned short* __restrict__ vb,    // [M][256]
                  const unsigned short* __restrict__ tqtkb, // [BS][512] tq|tk
                  const int* __restrict__ valid,
                  unsigned short* __restrict__ ao) {
  __shared__ __align__(16) char KsB[256 * 128];   // K' swizzled; merge alias
  __shared__ __align__(16) char VsB[32 * 512];    // V^T swizzled
  __shared__ float Lm[8 * 64];                    // merge lrun

  const int bh = blockIdx.x;
  const int bn = bh >> 3, h = bh & 7;
  const int b = bn >> 5, n = bn & 31;
  const int tid = threadIdx.x, l = tid & 63, w = tid >> 6;  // w in 0..15
  const int p = w >> 1, e = w & 1;
  const int lq = l & 31, hi = l >> 5;
  const int qa = p * 32 + lq;          // this lane's query row

  const unsigned long long bm0 = __ballot(valid[((b << 8) + 0   + l) * 32 + n] != 0);
  const unsigned long long bm1 = __ballot(valid[((b << 8) + 64  + l) * 32 + n] != 0);
  const unsigned long long bm2 = __ballot(valid[((b << 8) + 128 + l) * 32 + n] != 0);
  const unsigned long long bm3 = __ballot(valid[((b << 8) + 192 + l) * 32 + n] != 0);

  // Q' fragments (B-operand): col = own q, k = 8*hi + j per 16-wide K chunk.
  // q columns pre-scaled by c2, tq by 0.25*c2 (folded at GEMM).
  short8 qf[4];
  {
    const unsigned short* qp = &qkb[((bn << 8) + qa) * 512 + (h << 5)];
    const unsigned short* tp = &tqtkb[((b << 8) + qa) * 512 + (h << 5)];
    qf[0] = *(const short8*)&qp[hi * 8];
    qf[1] = *(const short8*)&qp[16 + hi * 8];
    qf[2] = *(const short8*)&tp[hi * 8];
    qf[3] = *(const short8*)&tp[16 + hi * 8];
  }

  // stage K' (k | tk), swizzled: byte = key*128 + ((c*16) ^ ((key&7)<<4))
#pragma unroll
  for (int i = 0; i < 2; ++i) {
    const int e2 = i * 1024 + tid;
    const int key = e2 >> 3, c = e2 & 7;
    const unsigned short* src = (c < 4)
        ? &qkb[((bn << 8) + key) * 512 + 256 + (h << 5) + c * 8]
        : &tqtkb[((b << 8) + key) * 512 + 256 + (h << 5) + (c - 4) * 8];
    *(short8*)(KsB + key * 128 + ((c * 16) ^ ((key & 7) << 4))) = *(const short8*)src;
  }
  // stage V^T, swizzled: byte = dv*512 + ((key*2) ^ ((dv&7)<<4))
  {
    const int key = tid >> 2, c = tid & 3;
    const short8 v = *(const short8*)&vb[((bn << 8) + key) * 256 + (h << 5) + c * 8];
#pragma unroll
    for (int j = 0; j < 8; ++j) {
      const int dv = c * 8 + j;
      *(unsigned short*)(VsB + dv * 512 + ((key * 2) ^ ((dv & 7) << 4))) =
          (unsigned short)v[j];
    }
  }
  __syncthreads();

  f32x16 oacc = {};
  float lrun = 0.0f;

  for (int g = e; g <= p; g += 2) {
    const int kbase = g << 5;
    // S^T = mfma(K'_tile, Q') -- log2 domain (scale folded)
    f32x16 s = {};
#pragma unroll
    for (int df = 0; df < 4; ++df) {
      const int key = kbase + lq;
      const short8 akf = *(const short8*)(
          KsB + key * 128 + ((df * 32 + hi * 16) ^ ((key & 7) << 4)));
      s = __builtin_amdgcn_mfma_f32_32x32x16_bf16(akf, qf[df], s, 0, 0, 0);
    }
    const unsigned long long bmc = (kbase < 64) ? bm0 : (kbase < 128) ? bm1
                                 : (kbase < 192) ? bm2 : bm3;
    const unsigned wnd = (kbase & 32) ? (unsigned)(bmc >> 32) : (unsigned)bmc;
    // p = masked ? 0 : exp2(s)
    float pr[16];
#pragma unroll
    for (int r = 0; r < 16; ++r) {
      const int crow = (r & 3) + 8 * (r >> 2) + 4 * hi;
      const int key = kbase + crow;
      const bool ok = (key <= qa) && (((wnd >> crow) & 1u) != 0u);
      pr[r] = ok ? __builtin_amdgcn_exp2f(s[r]) : 0.0f;
    }
    float rs = ((pr[0] + pr[1]) + (pr[2] + pr[3])) + ((pr[4] + pr[5]) + (pr[6] + pr[7]))
             + ((pr[8] + pr[9]) + (pr[10] + pr[11])) + ((pr[12] + pr[13]) + (pr[14] + pr[15]));
    rs += __shfl_xor(rs, 32);
    lrun += rs;
    // pack to bf16 pairs, exchange halves via shfl_xor(32)
    unsigned wds[8];
#pragma unroll
    for (int i2 = 0; i2 < 8; ++i2)
      wds[i2] = (unsigned)f2bf(pr[2 * i2]) | ((unsigned)f2bf(pr[2 * i2 + 1]) << 16);
    unsigned xw[8];
#pragma unroll
    for (int i2 = 0; i2 < 8; ++i2)
      xw[i2] = (unsigned)__shfl_xor((int)wds[i2], 32);
    i32x4 f0, f1;
    f0[0] = (int)(hi ? xw[2] : wds[0]);
    f0[1] = (int)(hi ? xw[3] : wds[1]);
    f0[2] = (int)(hi ? wds[2] : xw[0]);
    f0[3] = (int)(hi ? wds[3] : xw[1]);
    f1[0] = (int)(hi ? xw[6] : wds[4]);
    f1[1] = (int)(hi ? xw[7] : wds[5]);
    f1[2] = (int)(hi ? wds[6] : xw[4]);
    f1[3] = (int)(hi ? wds[7] : xw[5]);
    const short8 pf0 = __builtin_bit_cast(short8, f0);
    const short8 pf1 = __builtin_bit_cast(short8, f1);
    // PV: O^T += mfma(V^T, P)
    {
      const short8 avf = *(const short8*)(
          VsB + lq * 512 + (((kbase + hi * 8) * 2) ^ ((lq & 7) << 4)));
      oacc = __builtin_amdgcn_mfma_f32_32x32x16_bf16(avf, pf0, oacc, 0, 0, 0);
    }
    {
      const short8 avf = *(const short8*)(
          VsB + lq * 512 + (((kbase + 16 + hi * 8) * 2) ^ ((lq & 7) << 4)));
      oacc = __builtin_amdgcn_mfma_f32_32x32x16_bf16(avf, pf1, oacc, 0, 0, 0);
    }
  }

  // ---- merge the two partial states of each pair (pure addition) ----
  __syncthreads();   // all compute reads of KsB done -> safe to alias
  if (e == 1) {
    float* mo = (float*)(KsB + p * 4096);
#pragma unroll
    for (int r = 0; r < 16; ++r) mo[r * 64 + l] = oacc[r];   // [r][lane]
    Lm[p * 64 + l] = lrun;
  }
  __syncthreads();
  if (e == 0) {
    const float* mo = (const float*)(KsB + p * 4096);
#pragma unroll
    for (int r = 0; r < 16; ++r) oacc[r] += mo[r * 64 + l];
    lrun += Lm[p * 64 + l];

    // degenerate rows: no valid causal key -> uniform over ALL valid keys
    if (lrun == 0.0f) {
      float cnt = 0.0f;
      f32x16 os = {};
      for (int key = 0; key < 256; ++key) {
        const unsigned long long bmc = (key < 64) ? bm0 : (key < 128) ? bm1
                                     : (key < 192) ? bm2 : bm3;
        if ((bmc >> (key & 63)) & 1ull) {
          cnt += 1.0f;
#pragma unroll
          for (int r = 0; r < 16; ++r) {
            const int dv = (r & 3) + 8 * (r >> 2) + 4 * hi;
            os[r] += bf2f(*(const unsigned short*)(
                VsB + dv * 512 + ((key * 2) ^ ((dv & 7) << 4))));
          }
        }
      }
      oacc = os; lrun = cnt;
    }

    // direct store: lane holds O^T[dv=crow(r,hi)][q=lq]; 4 dv -> 8B packets
    const float inv = 1.0f / fmaxf(lrun, 1e-6f);
    const int row = (bn << 8) + qa;
#pragma unroll
    for (int g2 = 0; g2 < 4; ++g2) {
      const unsigned long long h0 = f2bf(oacc[4 * g2 + 0] * inv);
      const unsigned long long h1 = f2bf(oacc[4 * g2 + 1] * inv);
      const unsigned long long h2 = f2bf(oacc[4 * g2 + 2] * inv);
      const unsigned long long h3 = f2bf(oacc[4 * g2 + 3] * inv);
      const unsigned long long pkt = h0 | (h1 << 16) | (h2 << 32) | (h3 << 48);
      *(unsigned long long*)&ao[row * 256 + (h << 5) + 8 * g2 + 4 * hi] = pkt;
    }
  }
}

// ---------------------------------------------------------------------------
// LN1: fp32 in -> bf16 out (flat). LN2: fp32 in -> fp32 out, *valid, scatter.
// ---------------------------------------------------------------------------
__global__ __launch_bounds__(256)
void ln1_kernel(const float* __restrict__ X, const float* __restrict__ g,
                const float* __restrict__ bb, unsigned short* __restrict__ out) {
  const int row = blockIdx.x * 4 + (threadIdx.x >> 6);
  const int lane = threadIdx.x & 63;
  const float4 x = *(const float4*)&X[row * 256 + lane * 4];
  float s1 = x.x + x.y + x.z + x.w;
#pragma unroll
  for (int off = 1; off < 64; off <<= 1) s1 += __shfl_xor(s1, off);
  const float mean = s1 * (1.0f / 256.0f);
  const float dx = x.x - mean, dy = x.y - mean, dz = x.z - mean, dw = x.w - mean;
  float s2 = dx * dx + dy * dy + dz * dz + dw * dw;
#pragma unroll
  for (int off = 1; off < 64; off <<= 1) s2 += __shfl_xor(s2, off);
  const float rstd = rsqrtf(s2 * (1.0f / 256.0f) + 1e-5f);
  const int c0 = lane * 4;
  short4v y;
  y[0] = (short)f2bf(dx * rstd * g[c0] + bb[c0]);
  y[1] = (short)f2bf(dy * rstd * g[c0 + 1] + bb[c0 + 1]);
  y[2] = (short)f2bf(dz * rstd * g[c0 + 2] + bb[c0 + 2]);
  y[3] = (short)f2bf(dw * rstd * g[c0 + 3] + bb[c0 + 3]);
  *(short4v*)&out[row * 256 + c0] = y;
}

__global__ __launch_bounds__(256)
void ln2_kernel(const float* __restrict__ X, const float* __restrict__ g,
                const float* __restrict__ bb, float* __restrict__ out,
                const int* __restrict__ valid) {
  const int row = blockIdx.x * 4 + (threadIdx.x >> 6);
  const int lane = threadIdx.x & 63;
  const float4 x = *(const float4*)&X[row * 256 + lane * 4];
  float s1 = x.x + x.y + x.z + x.w;
#pragma unroll
  for (int off = 1; off < 64; off <<= 1) s1 += __shfl_xor(s1, off);
  const float mean = s1 * (1.0f / 256.0f);
  const float dx = x.x - mean, dy = x.y - mean, dz = x.z - mean, dw = x.w - mean;
  float s2 = dx * dx + dy * dy + dz * dz + dw * dw;
#pragma unroll
  for (int off = 1; off < 64; off <<= 1) s2 += __shfl_xor(s2, off);
  const float rstd = rsqrtf(s2 * (1.0f / 256.0f) + 1e-5f);
  const int c0 = lane * 4;
  const int bn = row >> 8, s = row & 255;
  const int b = bn >> 5, n = bn & 31;
  const float vmv = (valid[((b << 8) + s) * 32 + n] != 0) ? 1.0f : 0.0f;
  float4 y;
  y.x = (dx * rstd * g[c0] + bb[c0]) * vmv;
  y.y = (dy * rstd * g[c0 + 1] + bb[c0 + 1]) * vmv;
  y.z = (dz * rstd * g[c0 + 2] + bb[c0 + 2]) * vmv;
  y.w = (dw * rstd * g[c0 + 3] + bb[c0 + 3]) * vmv;
  *(float4*)&out[(((((b << 8) + s) << 5) + n) << 8) + c0] = y;
}

// ---------------------------------------------------------------------------
extern "C" void kernel_launch(void* const* d_in, const int* in_sizes, int n_in,
                              void* d_out, int out_size, void* d_ws, size_t ws_size,
                              hipStream_t stream) {
  const float* seq    = (const float*)d_in[0];
  const float* regs   = (const float*)d_in[1];
  const float* trs    = (const float*)d_in[2];
  const float* q_w    = (const float*)d_in[3];
  const float* q_b    = (const float*)d_in[4];
  const float* k_w    = (const float*)d_in[5];
  const float* k_b    = (const float*)d_in[6];
  const float* v_w    = (const float*)d_in[7];
  const float* v_b    = (const float*)d_in[8];
  const float* o_w    = (const float*)d_in[9];
  const float* o_b    = (const float*)d_in[10];
  const float* semb   = (const float*)d_in[11];
  const float* reg_w  = (const float*)d_in[12];
  const float* reg_b  = (const float*)d_in[13];
  const float* tr_w   = (const float*)d_in[14];
  const float* tr_b   = (const float*)d_in[15];
  const float* tq_w   = (const float*)d_in[16];
  const float* tq_b   = (const float*)d_in[17];
  const float* tk_w   = (const float*)d_in[18];
  const float* tk_b   = (const float*)d_in[19];
  const float* ff_w1  = (const float*)d_in[20];
  const float* ff_b1  = (const float*)d_in[21];
  const float* ff_w2  = (const float*)d_in[22];
  const float* ff_b2  = (const float*)d_in[23];
  const float* ln1_g  = (const float*)d_in[24];
  const float* ln1_b  = (const float*)d_in[25];
  const float* ln2_g  = (const float*)d_in[26];
  const float* ln2_b  = (const float*)d_in[27];
  const int*   valid  = (const int*)d_in[28];
  const int*   codes  = (const int*)d_in[29];

  float* f32ws = (float*)d_ws;
  float* ts    = f32ws;                 // 262144 f
  float* x1pre = f32ws + 262144;        // 8388608 f (reused as x2)
  unsigned short* bws = (unsigned short*)(f32ws + 262144 + 8388608);
  unsigned short* flatb = bws;                    // 8388608  (x1b alias)
  unsigned short* fpb   = bws + 8388608;          // 8388608  (ao alias)
  unsigned short* qkb   = bws + 16777216;         // 16777216 (h1 alias)
  unsigned short* vb    = bws + 33554432;         // 8388608
  unsigned short* tqtkb = bws + 41943040;         // 524288
  unsigned short* wqk   = bws + 42467328;         // 131072
  unsigned short* wv    = bws + 42598400;         // 65536
  unsigned short* wo    = bws + 42663936;         // 65536
  unsigned short* wtqtk = bws + 42729472;         // 131072
  unsigned short* wff1  = bws + 42860544;         // 131072
  unsigned short* wff2  = bws + 42991616;         // 131072  (end 43122688)
  unsigned short* ao  = fpb;
  unsigned short* x1b = flatb;
  unsigned short* h1  = qkb;
  float* x2 = x1pre;
  float* outp = (float*)d_out;

  const float c2 = 0.25505402f;  // (1/sqrt(32)) * log2(e) -- folded into q/tq

  // 1. time state + weight conversion (independent)
  ts_kernel<<<BS_, 256, 0, stream>>>(regs, trs, codes, semb, reg_w, reg_b,
                                     tr_w, tr_b, ts);
  cvtall_kernel<<<2560, 256, 0, stream>>>(q_w, k_w, v_w, o_w, tq_w, tk_w,
                                          ff_w1, ff_w2, wqk, wv, wo, wtqtk,
                                          wff1, wff2);
  // 2. prep: flatb = bf16(flat), fpb = bf16(flat + ts)
  prep_kernel<<<M_ / 8, 256, 0, stream>>>(seq, ts, flatb, fpb);
  // 3. temporal projections merged (tq|tk); 0.25*c2 folded into tq half
  mmb_kernel<0, 0, false, 256, 512, true, true, true>
      <<<dim3(8, 4), 256, 0, stream>>>(ts, wtqtk, tq_b, tk_b, nullptr,
                                       tqtkb, 0.25f * c2);
  // 4. q|k merged projection (c2 folded into q half); v projection
  mmb_kernel<3, 0, false, 256, 512, true, true, true>
      <<<dim3(256, 4), 256, 0, stream>>>(fpb, wqk, q_b, k_b, nullptr,
                                         qkb, c2);
  mmb_kernel<3, 0, false, 256, 256, true, false, false>
      <<<dim3(256, 2), 256, 0, stream>>>(flatb, wv, v_b, nullptr, nullptr,
                                         vb, 1.0f);
  // 5. attention (v6: split-key wave pairs)
  attn5_kernel<<<BN_ * NH_, 1024, 0, stream>>>(qkb, vb, tqtkb, valid, ao);
  // 6. o-proj + flat residual (bf16) -> x1pre (fp32); LN1 -> x1b (bf16)
  mmb_kernel<3, 2, false, 256, 256, false, false, false>
      <<<dim3(256, 2), 256, 0, stream>>>(ao, wo, o_b, nullptr, flatb,
                                         x1pre, 1.0f);
  ln1_kernel<<<M_ / 4, 256, 0, stream>>>(x1pre, ln1_g, ln1_b, x1b);
  // 7. FF
  mmb_kernel<3, 0, true, 256, 512, true, false, false>
      <<<dim3(256, 4), 256, 0, stream>>>(x1b, wff1, ff_b1, nullptr, nullptr,
                                         h1, 1.0f);
  mmb_kernel<3, 2, false, 512, 256, false, false, false>
      <<<dim3(256, 2), 256, 0, stream>>>(h1, wff2, ff_b2, nullptr, x1b,
                                         x2, 1.0f);
  // 8. LN2 * valid -> output layout
  ln2_kernel<<<M_ / 4, 256, 0, stream>>>(x2, ln2_g, ln2_b, outp, valid);
}

// Round 9
// 299.061 us; speedup vs baseline: 1.2002x; 1.2002x over previous
//
#include <hip/hip_runtime.h>
#include <math.h>

// Shapes (fixed)
#define B_ 4
#define S_ 256
#define N_ 32
#define H_ 256
#define NH_ 8
#define HD_ 32
#define FF_ 512
#define BN_ 128
#define M_ 32768   // BN_*S_
#define BS_ 1024   // B_*S_

typedef __attribute__((ext_vector_type(8))) short short8;
typedef __attribute__((ext_vector_type(4))) short short4v;
typedef __attribute__((ext_vector_type(4))) float f32x4;
typedef __attribute__((ext_vector_type(16))) float f32x16;
typedef __attribute__((ext_vector_type(4))) int i32x4;

__device__ __forceinline__ unsigned short f2bf(float f) {
  unsigned u = __builtin_bit_cast(unsigned, f);
  u = (u + 0x7FFFu + ((u >> 16) & 1u)) >> 16;
  return (unsigned short)u;
}
__device__ __forceinline__ float bf2f(unsigned short h) {
  unsigned u = ((unsigned)h) << 16;
  return __builtin_bit_cast(float, u);
}

// Direct global->LDS DMA, 16B per lane (lands at ldsbase + lane*16).
__device__ __forceinline__ void gload16(const void* g, void* l) {
  __builtin_amdgcn_global_load_lds(
      (const __attribute__((address_space(1))) unsigned*)g,
      (__attribute__((address_space(3))) unsigned*)l, 16, 0, 0);
}

// ---------------------------------------------------------------------------
// time_state[bs, h] (fp32)
// ---------------------------------------------------------------------------
__global__ __launch_bounds__(256)
void ts_kernel(const float* __restrict__ reg, const float* __restrict__ tr,
               const int* __restrict__ codes,
               const float* __restrict__ sess_emb,
               const float* __restrict__ reg_w, const float* __restrict__ reg_b,
               const float* __restrict__ tr_w, const float* __restrict__ tr_b,
               float* __restrict__ ts) {
  const int bs = blockIdx.x;
  const int h = threadIdx.x;
  int c = codes[bs];
  c = c < 0 ? 0 : (c > 7 ? 7 : c);
  const float r = reg[bs], t = tr[bs];
  ts[bs * H_ + h] = sess_emb[c * H_ + h] + r * reg_w[h] + reg_b[h]
                    + t * tr_w[h] + tr_b[h];
}

// ---------------------------------------------------------------------------
// All weight conversions in one launch. W[K][N] fp32 -> Wt[N][K] bf16.
// ---------------------------------------------------------------------------
__global__ __launch_bounds__(256)
void cvtall_kernel(const float* __restrict__ q_w, const float* __restrict__ k_w,
                   const float* __restrict__ v_w, const float* __restrict__ o_w,
                   const float* __restrict__ tq_w, const float* __restrict__ tk_w,
                   const float* __restrict__ ff1_w, const float* __restrict__ ff2_w,
                   unsigned short* __restrict__ wqk, unsigned short* __restrict__ wv,
                   unsigned short* __restrict__ wo, unsigned short* __restrict__ wtqtk,
                   unsigned short* __restrict__ wff1, unsigned short* __restrict__ wff2) {
  const int bid = blockIdx.x, tid = threadIdx.x;
  const float* src; unsigned short* dst; int ns, K, base;
  if (bid < 256)       { src = q_w;   dst = wqk;           ns = 8; K = 256; base = 0; }
  else if (bid < 512)  { src = k_w;   dst = wqk + 65536;   ns = 8; K = 256; base = 256; }
  else if (bid < 768)  { src = v_w;   dst = wv;            ns = 8; K = 256; base = 512; }
  else if (bid < 1024) { src = o_w;   dst = wo;            ns = 8; K = 256; base = 768; }
  else if (bid < 1280) { src = tq_w;  dst = wtqtk;         ns = 8; K = 256; base = 1024; }
  else if (bid < 1536) { src = tk_w;  dst = wtqtk + 65536; ns = 8; K = 256; base = 1280; }
  else if (bid < 2048) { src = ff1_w; dst = wff1;          ns = 9; K = 256; base = 1536; }
  else                 { src = ff2_w; dst = wff2;          ns = 8; K = 512; base = 2048; }
  const int idx = (bid - base) * 256 + tid;
  const int k = idx >> ns, n = idx & ((1 << ns) - 1);
  dst[n * K + k] = f2bf(src[idx]);
}

// ---------------------------------------------------------------------------
// Prep: flatb = bf16(seq gathered to [M,256]); fpb = bf16(seq + ts).
// ---------------------------------------------------------------------------
__global__ __launch_bounds__(256)
void prep_kernel(const float* __restrict__ seq, const float* __restrict__ ts,
                 unsigned short* __restrict__ flatb, unsigned short* __restrict__ fpb) {
  const int row = blockIdx.x * 8 + (threadIdx.x >> 5);
  const int c0 = (threadIdx.x & 31) * 8;
  const int bn = row >> 8, s = row & 255;
  const int b = bn >> 5, n = bn & 31;
  const float* sp = &seq[((((b << 8) + s) << 5) + n) * 256 + c0];
  const float* tp = &ts[(((b << 8) + s) << 8) + c0];
  const float4 a0 = *(const float4*)sp, a1 = *(const float4*)(sp + 4);
  const float4 t0 = *(const float4*)tp, t1 = *(const float4*)(tp + 4);
  short8 fv, gv;
  fv[0] = (short)f2bf(a0.x); fv[1] = (short)f2bf(a0.y);
  fv[2] = (short)f2bf(a0.z); fv[3] = (short)f2bf(a0.w);
  fv[4] = (short)f2bf(a1.x); fv[5] = (short)f2bf(a1.y);
  fv[6] = (short)f2bf(a1.z); fv[7] = (short)f2bf(a1.w);
  gv[0] = (short)f2bf(a0.x + t0.x); gv[1] = (short)f2bf(a0.y + t0.y);
  gv[2] = (short)f2bf(a0.z + t0.z); gv[3] = (short)f2bf(a0.w + t0.w);
  gv[4] = (short)f2bf(a1.x + t1.x); gv[5] = (short)f2bf(a1.y + t1.y);
  gv[6] = (short)f2bf(a1.z + t1.z); gv[7] = (short)f2bf(a1.w + t1.w);
  *(short8*)&flatb[row * 256 + c0] = fv;
  *(short8*)&fpb[row * 256 + c0] = gv;
}

// ---------------------------------------------------------------------------
// bf16 MFMA GEMM: C[M,NOUT] = epilogue(A @ W + bias)
// AMODE: 0 = fp32 A[M,K] (padded LDS, reg staging);
//        3 = bf16 A[M,K] (linear LDS, global_load_lds direct staging)
// RESMODE: 0 none; 2 + resb (bf16 [M,NOUT])
// DUALB: bias for col<256, bias2 for col>=256. SCALEH: post_scale only col<256.
// ---------------------------------------------------------------------------
template<int AMODE, int RESMODE, bool GELU_, int K, int NOUT, bool OUTBF,
         bool DUALB, bool SCALEH>
__global__ __launch_bounds__(256)
void mmb_kernel(const void* __restrict__ Av, const unsigned short* __restrict__ Wt,
                const float* __restrict__ bias, const float* __restrict__ bias2,
                const unsigned short* __restrict__ resb,
                void* __restrict__ Cv, float post_scale) {
  constexpr int LDA = (AMODE == 3) ? 64 : 72;
  constexpr int LDB = (AMODE == 3) ? 64 : 72;
  __shared__ unsigned short As[128 * 72];
  __shared__ unsigned short Bs[128 * 72];
  const int tid = threadIdx.x;
  const int m0 = blockIdx.x * 128, n0 = blockIdx.y * 128;
  const int l = tid & 63, w = tid >> 6;
  const int wr = w >> 1, wc = w & 1;
  const int lr = l & 15, lg = l >> 4;
  f32x4 acc[4][4] = {};

  // per-lane global bases for direct staging (AMODE==3)
  const unsigned short* ga = nullptr;
  const unsigned short* gb = nullptr;
  if (AMODE == 3) {
    ga = (const unsigned short*)Av + (m0 + w * 32 + (l >> 3)) * K + (l & 7) * 8;
    gb = Wt + (n0 + w * 32 + (l >> 3)) * K + (l & 7) * 8;
  }

  for (int k0 = 0; k0 < K; k0 += 64) {
    if (AMODE == 3) {
      // direct global->LDS: 4 insts each for A and B per wave (8 rows/inst)
#pragma unroll
      for (int i = 0; i < 4; ++i) {
        gload16(ga + k0 + i * 8 * K, &As[(w * 32 + i * 8) * 64]);
        gload16(gb + k0 + i * 8 * K, &Bs[(w * 32 + i * 8) * 64]);
      }
    } else {
#pragma unroll
      for (int i = 0; i < 8; ++i) {
        const int seg = i * 256 + tid;
        const int r = seg >> 4, c4 = (seg & 15) * 4;
        const float4 a4 = *(const float4*)&((const float*)Av)[(m0 + r) * K + k0 + c4];
        short4v sv;
        sv[0] = (short)f2bf(a4.x); sv[1] = (short)f2bf(a4.y);
        sv[2] = (short)f2bf(a4.z); sv[3] = (short)f2bf(a4.w);
        *(short4v*)&As[r * LDA + c4] = sv;
      }
#pragma unroll
      for (int i = 0; i < 4; ++i) {
        const int seg = i * 256 + tid;
        const int n = seg >> 3, c8 = (seg & 7) * 8;
        const short8 v = *(const short8*)&Wt[(n0 + n) * K + k0 + c8];
        *(short8*)&Bs[n * LDB + c8] = v;
      }
    }
    __syncthreads();
#pragma unroll
    for (int ks = 0; ks < 2; ++ks) {
      short8 af[4], bfr[4];
#pragma unroll
      for (int qt = 0; qt < 4; ++qt)
        af[qt] = *(const short8*)&As[(wr * 64 + qt * 16 + lr) * LDA + ks * 32 + lg * 8];
#pragma unroll
      for (int nt = 0; nt < 4; ++nt)
        bfr[nt] = *(const short8*)&Bs[(wc * 64 + nt * 16 + lr) * LDB + ks * 32 + lg * 8];
#pragma unroll
      for (int qt = 0; qt < 4; ++qt)
#pragma unroll
        for (int nt = 0; nt < 4; ++nt)
          acc[qt][nt] = __builtin_amdgcn_mfma_f32_16x16x32_bf16(
              af[qt], bfr[nt], acc[qt][nt], 0, 0, 0);
    }
    __syncthreads();
  }

#pragma unroll
  for (int qt = 0; qt < 4; ++qt) {
#pragma unroll
    for (int nt = 0; nt < 4; ++nt) {
      const int col = n0 + wc * 64 + nt * 16 + lr;
      const float bsv = DUALB ? (col < 256 ? bias[col] : bias2[col - 256])
                              : bias[col];
      const float sc = SCALEH ? (col < 256 ? post_scale : 1.0f) : post_scale;
#pragma unroll
      for (int i = 0; i < 4; ++i) {
        const int row = m0 + wr * 64 + qt * 16 + (lg << 2) + i;
        float v = (acc[qt][nt][i] + bsv) * sc;
        if (RESMODE == 2) v += bf2f(resb[row * NOUT + col]);
        if (GELU_) v = 0.5f * v * (1.0f + erff(v * 0.70710678118654752f));
        if (OUTBF) ((unsigned short*)Cv)[row * NOUT + col] = f2bf(v);
        else       ((float*)Cv)[row * NOUT + col] = v;
      }
    }
  }
}

// ---------------------------------------------------------------------------
// Attention v6b: split-key wave pairs (no-max softmax => partials add).
// 1024 thr = 16 waves. Pair p = w>>1 owns query chunk p; parity e = w&1
// handles key groups g == e (mod 2), g <= p  ->  max 4 serial groups/wave.
// __launch_bounds__(1024, 4): VGPR cap 128 (v6's (1024,8) capped at 32 and
// spilled everything -- WRITE_SIZE 273MB of scratch traffic).
// ---------------------------------------------------------------------------
__global__ __launch_bounds__(1024, 4)
void attn5_kernel(const unsigned short* __restrict__ qkb,   // [M][512] q|k
                  const unsigned short* __restrict__ vb,    // [M][256]
                  const unsigned short* __restrict__ tqtkb, // [BS][512] tq|tk
                  const int* __restrict__ valid,
                  unsigned short* __restrict__ ao) {
  __shared__ __align__(16) char KsB[256 * 128];   // K' swizzled; merge alias
  __shared__ __align__(16) char VsB[32 * 512];    // V^T swizzled
  __shared__ float Lm[8 * 64];                    // merge lrun

  const int bh = blockIdx.x;
  const int bn = bh >> 3, h = bh & 7;
  const int b = bn >> 5, n = bn & 31;
  const int tid = threadIdx.x, l = tid & 63, w = tid >> 6;  // w in 0..15
  const int p = w >> 1, e = w & 1;
  const int lq = l & 31, hi = l >> 5;
  const int qa = p * 32 + lq;          // this lane's query row

  const unsigned long long bm0 = __ballot(valid[((b << 8) + 0   + l) * 32 + n] != 0);
  const unsigned long long bm1 = __ballot(valid[((b << 8) + 64  + l) * 32 + n] != 0);
  const unsigned long long bm2 = __ballot(valid[((b << 8) + 128 + l) * 32 + n] != 0);
  const unsigned long long bm3 = __ballot(valid[((b << 8) + 192 + l) * 32 + n] != 0);

  // Q' fragments (B-operand): col = own q, k = 8*hi + j per 16-wide K chunk.
  // q columns pre-scaled by c2, tq by 0.25*c2 (folded at GEMM).
  short8 qf[4];
  {
    const unsigned short* qp = &qkb[((bn << 8) + qa) * 512 + (h << 5)];
    const unsigned short* tp = &tqtkb[((b << 8) + qa) * 512 + (h << 5)];
    qf[0] = *(const short8*)&qp[hi * 8];
    qf[1] = *(const short8*)&qp[16 + hi * 8];
    qf[2] = *(const short8*)&tp[hi * 8];
    qf[3] = *(const short8*)&tp[16 + hi * 8];
  }

  // stage K' (k | tk), swizzled: byte = key*128 + ((c*16) ^ ((key&7)<<4))
#pragma unroll
  for (int i = 0; i < 2; ++i) {
    const int e2 = i * 1024 + tid;
    const int key = e2 >> 3, c = e2 & 7;
    const unsigned short* src = (c < 4)
        ? &qkb[((bn << 8) + key) * 512 + 256 + (h << 5) + c * 8]
        : &tqtkb[((b << 8) + key) * 512 + 256 + (h << 5) + (c - 4) * 8];
    *(short8*)(KsB + key * 128 + ((c * 16) ^ ((key & 7) << 4))) = *(const short8*)src;
  }
  // stage V^T, swizzled: byte = dv*512 + ((key*2) ^ ((dv&7)<<4))
  {
    const int key = tid >> 2, c = tid & 3;
    const short8 v = *(const short8*)&vb[((bn << 8) + key) * 256 + (h << 5) + c * 8];
#pragma unroll
    for (int j = 0; j < 8; ++j) {
      const int dv = c * 8 + j;
      *(unsigned short*)(VsB + dv * 512 + ((key * 2) ^ ((dv & 7) << 4))) =
          (unsigned short)v[j];
    }
  }
  __syncthreads();

  f32x16 oacc = {};
  float lrun = 0.0f;

  for (int g = e; g <= p; g += 2) {
    const int kbase = g << 5;
    // S^T = mfma(K'_tile, Q') -- log2 domain (scale folded)
    f32x16 s = {};
#pragma unroll
    for (int df = 0; df < 4; ++df) {
      const int key = kbase + lq;
      const short8 akf = *(const short8*)(
          KsB + key * 128 + ((df * 32 + hi * 16) ^ ((key & 7) << 4)));
      s = __builtin_amdgcn_mfma_f32_32x32x16_bf16(akf, qf[df], s, 0, 0, 0);
    }
    const unsigned long long bmc = (kbase < 64) ? bm0 : (kbase < 128) ? bm1
                                 : (kbase < 192) ? bm2 : bm3;
    const unsigned wnd = (kbase & 32) ? (unsigned)(bmc >> 32) : (unsigned)bmc;
    // p = masked ? 0 : exp2(s)
    float pr[16];
#pragma unroll
    for (int r = 0; r < 16; ++r) {
      const int crow = (r & 3) + 8 * (r >> 2) + 4 * hi;
      const int key = kbase + crow;
      const bool ok = (key <= qa) && (((wnd >> crow) & 1u) != 0u);
      pr[r] = ok ? __builtin_amdgcn_exp2f(s[r]) : 0.0f;
    }
    float rs = ((pr[0] + pr[1]) + (pr[2] + pr[3])) + ((pr[4] + pr[5]) + (pr[6] + pr[7]))
             + ((pr[8] + pr[9]) + (pr[10] + pr[11])) + ((pr[12] + pr[13]) + (pr[14] + pr[15]));
    rs += __shfl_xor(rs, 32);
    lrun += rs;
    // pack to bf16 pairs, exchange halves via shfl_xor(32)
    unsigned wds[8];
#pragma unroll
    for (int i2 = 0; i2 < 8; ++i2)
      wds[i2] = (unsigned)f2bf(pr[2 * i2]) | ((unsigned)f2bf(pr[2 * i2 + 1]) << 16);
    unsigned xw[8];
#pragma unroll
    for (int i2 = 0; i2 < 8; ++i2)
      xw[i2] = (unsigned)__shfl_xor((int)wds[i2], 32);
    i32x4 f0, f1;
    f0[0] = (int)(hi ? xw[2] : wds[0]);
    f0[1] = (int)(hi ? xw[3] : wds[1]);
    f0[2] = (int)(hi ? wds[2] : xw[0]);
    f0[3] = (int)(hi ? wds[3] : xw[1]);
    f1[0] = (int)(hi ? xw[6] : wds[4]);
    f1[1] = (int)(hi ? xw[7] : wds[5]);
    f1[2] = (int)(hi ? wds[6] : xw[4]);
    f1[3] = (int)(hi ? wds[7] : xw[5]);
    const short8 pf0 = __builtin_bit_cast(short8, f0);
    const short8 pf1 = __builtin_bit_cast(short8, f1);
    // PV: O^T += mfma(V^T, P)
    {
      const short8 avf = *(const short8*)(
          VsB + lq * 512 + (((kbase + hi * 8) * 2) ^ ((lq & 7) << 4)));
      oacc = __builtin_amdgcn_mfma_f32_32x32x16_bf16(avf, pf0, oacc, 0, 0, 0);
    }
    {
      const short8 avf = *(const short8*)(
          VsB + lq * 512 + (((kbase + 16 + hi * 8) * 2) ^ ((lq & 7) << 4)));
      oacc = __builtin_amdgcn_mfma_f32_32x32x16_bf16(avf, pf1, oacc, 0, 0, 0);
    }
  }

  // ---- merge the two partial states of each pair (pure addition) ----
  __syncthreads();   // all compute reads of KsB done -> safe to alias
  if (e == 1) {
    float* mo = (float*)(KsB + p * 4096);
#pragma unroll
    for (int r = 0; r < 16; ++r) mo[r * 64 + l] = oacc[r];   // [r][lane]
    Lm[p * 64 + l] = lrun;
  }
  __syncthreads();
  if (e == 0) {
    const float* mo = (const float*)(KsB + p * 4096);
#pragma unroll
    for (int r = 0; r < 16; ++r) oacc[r] += mo[r * 64 + l];
    lrun += Lm[p * 64 + l];

    // degenerate rows: no valid causal key -> uniform over ALL valid keys
    if (lrun == 0.0f) {
      float cnt = 0.0f;
      f32x16 os = {};
      for (int key = 0; key < 256; ++key) {
        const unsigned long long bmc = (key < 64) ? bm0 : (key < 128) ? bm1
                                     : (key < 192) ? bm2 : bm3;
        if ((bmc >> (key & 63)) & 1ull) {
          cnt += 1.0f;
#pragma unroll
          for (int r = 0; r < 16; ++r) {
            const int dv = (r & 3) + 8 * (r >> 2) + 4 * hi;
            os[r] += bf2f(*(const unsigned short*)(
                VsB + dv * 512 + ((key * 2) ^ ((dv & 7) << 4))));
          }
        }
      }
      oacc = os; lrun = cnt;
    }

    // direct store: lane holds O^T[dv=crow(r,hi)][q=lq]; 4 dv -> 8B packets
    const float inv = 1.0f / fmaxf(lrun, 1e-6f);
    const int row = (bn << 8) + qa;
#pragma unroll
    for (int g2 = 0; g2 < 4; ++g2) {
      const unsigned long long h0 = f2bf(oacc[4 * g2 + 0] * inv);
      const unsigned long long h1 = f2bf(oacc[4 * g2 + 1] * inv);
      const unsigned long long h2 = f2bf(oacc[4 * g2 + 2] * inv);
      const unsigned long long h3 = f2bf(oacc[4 * g2 + 3] * inv);
      const unsigned long long pkt = h0 | (h1 << 16) | (h2 << 32) | (h3 << 48);
      *(unsigned long long*)&ao[row * 256 + (h << 5) + 8 * g2 + 4 * hi] = pkt;
    }
  }
}

// ---------------------------------------------------------------------------
// LN1: fp32 in -> bf16 out (flat). LN2: fp32 in -> fp32 out, *valid, scatter.
// ---------------------------------------------------------------------------
__global__ __launch_bounds__(256)
void ln1_kernel(const float* __restrict__ X, const float* __restrict__ g,
                const float* __restrict__ bb, unsigned short* __restrict__ out) {
  const int row = blockIdx.x * 4 + (threadIdx.x >> 6);
  const int lane = threadIdx.x & 63;
  const float4 x = *(const float4*)&X[row * 256 + lane * 4];
  float s1 = x.x + x.y + x.z + x.w;
#pragma unroll
  for (int off = 1; off < 64; off <<= 1) s1 += __shfl_xor(s1, off);
  const float mean = s1 * (1.0f / 256.0f);
  const float dx = x.x - mean, dy = x.y - mean, dz = x.z - mean, dw = x.w - mean;
  float s2 = dx * dx + dy * dy + dz * dz + dw * dw;
#pragma unroll
  for (int off = 1; off < 64; off <<= 1) s2 += __shfl_xor(s2, off);
  const float rstd = rsqrtf(s2 * (1.0f / 256.0f) + 1e-5f);
  const int c0 = lane * 4;
  short4v y;
  y[0] = (short)f2bf(dx * rstd * g[c0] + bb[c0]);
  y[1] = (short)f2bf(dy * rstd * g[c0 + 1] + bb[c0 + 1]);
  y[2] = (short)f2bf(dz * rstd * g[c0 + 2] + bb[c0 + 2]);
  y[3] = (short)f2bf(dw * rstd * g[c0 + 3] + bb[c0 + 3]);
  *(short4v*)&out[row * 256 + c0] = y;
}

__global__ __launch_bounds__(256)
void ln2_kernel(const float* __restrict__ X, const float* __restrict__ g,
                const float* __restrict__ bb, float* __restrict__ out,
                const int* __restrict__ valid) {
  const int row = blockIdx.x * 4 + (threadIdx.x >> 6);
  const int lane = threadIdx.x & 63;
  const float4 x = *(const float4*)&X[row * 256 + lane * 4];
  float s1 = x.x + x.y + x.z + x.w;
#pragma unroll
  for (int off = 1; off < 64; off <<= 1) s1 += __shfl_xor(s1, off);
  const float mean = s1 * (1.0f / 256.0f);
  const float dx = x.x - mean, dy = x.y - mean, dz = x.z - mean, dw = x.w - mean;
  float s2 = dx * dx + dy * dy + dz * dz + dw * dw;
#pragma unroll
  for (int off = 1; off < 64; off <<= 1) s2 += __shfl_xor(s2, off);
  const float rstd = rsqrtf(s2 * (1.0f / 256.0f) + 1e-5f);
  const int c0 = lane * 4;
  const int bn = row >> 8, s = row & 255;
  const int b = bn >> 5, n = bn & 31;
  const float vmv = (valid[((b << 8) + s) * 32 + n] != 0) ? 1.0f : 0.0f;
  float4 y;
  y.x = (dx * rstd * g[c0] + bb[c0]) * vmv;
  y.y = (dy * rstd * g[c0 + 1] + bb[c0 + 1]) * vmv;
  y.z = (dz * rstd * g[c0 + 2] + bb[c0 + 2]) * vmv;
  y.w = (dw * rstd * g[c0 + 3] + bb[c0 + 3]) * vmv;
  *(float4*)&out[(((((b << 8) + s) << 5) + n) << 8) + c0] = y;
}

// ---------------------------------------------------------------------------
extern "C" void kernel_launch(void* const* d_in, const int* in_sizes, int n_in,
                              void* d_out, int out_size, void* d_ws, size_t ws_size,
                              hipStream_t stream) {
  const float* seq    = (const float*)d_in[0];
  const float* regs   = (const float*)d_in[1];
  const float* trs    = (const float*)d_in[2];
  const float* q_w    = (const float*)d_in[3];
  const float* q_b    = (const float*)d_in[4];
  const float* k_w    = (const float*)d_in[5];
  const float* k_b    = (const float*)d_in[6];
  const float* v_w    = (const float*)d_in[7];
  const float* v_b    = (const float*)d_in[8];
  const float* o_w    = (const float*)d_in[9];
  const float* o_b    = (const float*)d_in[10];
  const float* semb   = (const float*)d_in[11];
  const float* reg_w  = (const float*)d_in[12];
  const float* reg_b  = (const float*)d_in[13];
  const float* tr_w   = (const float*)d_in[14];
  const float* tr_b   = (const float*)d_in[15];
  const float* tq_w   = (const float*)d_in[16];
  const float* tq_b   = (const float*)d_in[17];
  const float* tk_w   = (const float*)d_in[18];
  const float* tk_b   = (const float*)d_in[19];
  const float* ff_w1  = (const float*)d_in[20];
  const float* ff_b1  = (const float*)d_in[21];
  const float* ff_w2  = (const float*)d_in[22];
  const float* ff_b2  = (const float*)d_in[23];
  const float* ln1_g  = (const float*)d_in[24];
  const float* ln1_b  = (const float*)d_in[25];
  const float* ln2_g  = (const float*)d_in[26];
  const float* ln2_b  = (const float*)d_in[27];
  const int*   valid  = (const int*)d_in[28];
  const int*   codes  = (const int*)d_in[29];

  float* f32ws = (float*)d_ws;
  float* ts    = f32ws;                 // 262144 f
  float* x1pre = f32ws + 262144;        // 8388608 f (reused as x2)
  unsigned short* bws = (unsigned short*)(f32ws + 262144 + 8388608);
  unsigned short* flatb = bws;                    // 8388608  (x1b alias)
  unsigned short* fpb   = bws + 8388608;          // 8388608  (ao alias)
  unsigned short* qkb   = bws + 16777216;         // 16777216 (h1 alias)
  unsigned short* vb    = bws + 33554432;         // 8388608
  unsigned short* tqtkb = bws + 41943040;         // 524288
  unsigned short* wqk   = bws + 42467328;         // 131072
  unsigned short* wv    = bws + 42598400;         // 65536
  unsigned short* wo    = bws + 42663936;         // 65536
  unsigned short* wtqtk = bws + 42729472;         // 131072
  unsigned short* wff1  = bws + 42860544;         // 131072
  unsigned short* wff2  = bws + 42991616;         // 131072  (end 43122688)
  unsigned short* ao  = fpb;
  unsigned short* x1b = flatb;
  unsigned short* h1  = qkb;
  float* x2 = x1pre;
  float* outp = (float*)d_out;

  const float c2 = 0.25505402f;  // (1/sqrt(32)) * log2(e) -- folded into q/tq

  // 1. time state + weight conversion (independent)
  ts_kernel<<<BS_, 256, 0, stream>>>(regs, trs, codes, semb, reg_w, reg_b,
                                     tr_w, tr_b, ts);
  cvtall_kernel<<<2560, 256, 0, stream>>>(q_w, k_w, v_w, o_w, tq_w, tk_w,
                                          ff_w1, ff_w2, wqk, wv, wo, wtqtk,
                                          wff1, wff2);
  // 2. prep: flatb = bf16(flat), fpb = bf16(flat + ts)
  prep_kernel<<<M_ / 8, 256, 0, stream>>>(seq, ts, flatb, fpb);
  // 3. temporal projections merged (tq|tk); 0.25*c2 folded into tq half
  mmb_kernel<0, 0, false, 256, 512, true, true, true>
      <<<dim3(8, 4), 256, 0, stream>>>(ts, wtqtk, tq_b, tk_b, nullptr,
                                       tqtkb, 0.25f * c2);
  // 4. q|k merged projection (c2 folded into q half); v projection
  mmb_kernel<3, 0, false, 256, 512, true, true, true>
      <<<dim3(256, 4), 256, 0, stream>>>(fpb, wqk, q_b, k_b, nullptr,
                                         qkb, c2);
  mmb_kernel<3, 0, false, 256, 256, true, false, false>
      <<<dim3(256, 2), 256, 0, stream>>>(flatb, wv, v_b, nullptr, nullptr,
                                         vb, 1.0f);
  // 5. attention (v6b: split-key wave pairs, fixed launch bounds)
  attn5_kernel<<<BN_ * NH_, 1024, 0, stream>>>(qkb, vb, tqtkb, valid, ao);
  // 6. o-proj + flat residual (bf16) -> x1pre (fp32); LN1 -> x1b (bf16)
  mmb_kernel<3, 2, false, 256, 256, false, false, false>
      <<<dim3(256, 2), 256, 0, stream>>>(ao, wo, o_b, nullptr, flatb,
                                         x1pre, 1.0f);
  ln1_kernel<<<M_ / 4, 256, 0, stream>>>(x1pre, ln1_g, ln1_b, x1b);
  // 7. FF
  mmb_kernel<3, 0, true, 256, 512, true, false, false>
      <<<dim3(256, 4), 256, 0, stream>>>(x1b, wff1, ff_b1, nullptr, nullptr,
                                         h1, 1.0f);
  mmb_kernel<3, 2, false, 512, 256, false, false, false>
      <<<dim3(256, 2), 256, 0, stream>>>(h1, wff2, ff_b2, nullptr, x1b,
                                         x2, 1.0f);
  // 8. LN2 * valid -> output layout
  ln2_kernel<<<M_ / 4, 256, 0, stream>>>(x2, ln2_g, ln2_b, outp, valid);
}

// Round 10
// 190.543 us; speedup vs baseline: 1.8838x; 1.5695x over previous
//
#include <hip/hip_runtime.h>
#include <math.h>

// Shapes (fixed)
#define B_ 4
#define S_ 256
#define N_ 32
#define H_ 256
#define NH_ 8
#define HD_ 32
#define FF_ 512
#define BN_ 128
#define M_ 32768   // BN_*S_
#define BS_ 1024   // B_*S_

typedef __attribute__((ext_vector_type(8))) short short8;
typedef __attribute__((ext_vector_type(4))) short short4v;
typedef __attribute__((ext_vector_type(4))) float f32x4;
typedef __attribute__((ext_vector_type(16))) float f32x16;
typedef __attribute__((ext_vector_type(4))) int i32x4;

__device__ __forceinline__ unsigned short f2bf(float f) {
  unsigned u = __builtin_bit_cast(unsigned, f);
  u = (u + 0x7FFFu + ((u >> 16) & 1u)) >> 16;
  return (unsigned short)u;
}
__device__ __forceinline__ float bf2f(unsigned short h) {
  unsigned u = ((unsigned)h) << 16;
  return __builtin_bit_cast(float, u);
}

// Direct global->LDS DMA, 16B per lane (lands at ldsbase + lane*16).
__device__ __forceinline__ void gload16(const void* g, void* l) {
  __builtin_amdgcn_global_load_lds(
      (const __attribute__((address_space(1))) unsigned*)g,
      (__attribute__((address_space(3))) unsigned*)l, 16, 0, 0);
}

// ---------------------------------------------------------------------------
// time_state[bs, h] (fp32)
// ---------------------------------------------------------------------------
__global__ __launch_bounds__(256)
void ts_kernel(const float* __restrict__ reg, const float* __restrict__ tr,
               const int* __restrict__ codes,
               const float* __restrict__ sess_emb,
               const float* __restrict__ reg_w, const float* __restrict__ reg_b,
               const float* __restrict__ tr_w, const float* __restrict__ tr_b,
               float* __restrict__ ts) {
  const int bs = blockIdx.x;
  const int h = threadIdx.x;
  int c = codes[bs];
  c = c < 0 ? 0 : (c > 7 ? 7 : c);
  const float r = reg[bs], t = tr[bs];
  ts[bs * H_ + h] = sess_emb[c * H_ + h] + r * reg_w[h] + reg_b[h]
                    + t * tr_w[h] + tr_b[h];
}

// ---------------------------------------------------------------------------
// All weight conversions in one launch. W[K][N] fp32 -> Wt[N][K] bf16.
// ---------------------------------------------------------------------------
__global__ __launch_bounds__(256)
void cvtall_kernel(const float* __restrict__ q_w, const float* __restrict__ k_w,
                   const float* __restrict__ v_w, const float* __restrict__ o_w,
                   const float* __restrict__ tq_w, const float* __restrict__ tk_w,
                   const float* __restrict__ ff1_w, const float* __restrict__ ff2_w,
                   unsigned short* __restrict__ wqk, unsigned short* __restrict__ wv,
                   unsigned short* __restrict__ wo, unsigned short* __restrict__ wtqtk,
                   unsigned short* __restrict__ wff1, unsigned short* __restrict__ wff2) {
  const int bid = blockIdx.x, tid = threadIdx.x;
  const float* src; unsigned short* dst; int ns, K, base;
  if (bid < 256)       { src = q_w;   dst = wqk;           ns = 8; K = 256; base = 0; }
  else if (bid < 512)  { src = k_w;   dst = wqk + 65536;   ns = 8; K = 256; base = 256; }
  else if (bid < 768)  { src = v_w;   dst = wv;            ns = 8; K = 256; base = 512; }
  else if (bid < 1024) { src = o_w;   dst = wo;            ns = 8; K = 256; base = 768; }
  else if (bid < 1280) { src = tq_w;  dst = wtqtk;         ns = 8; K = 256; base = 1024; }
  else if (bid < 1536) { src = tk_w;  dst = wtqtk + 65536; ns = 8; K = 256; base = 1280; }
  else if (bid < 2048) { src = ff1_w; dst = wff1;          ns = 9; K = 256; base = 1536; }
  else                 { src = ff2_w; dst = wff2;          ns = 8; K = 512; base = 2048; }
  const int idx = (bid - base) * 256 + tid;
  const int k = idx >> ns, n = idx & ((1 << ns) - 1);
  dst[n * K + k] = f2bf(src[idx]);
}

// ---------------------------------------------------------------------------
// Prep: flatb = bf16(seq gathered to [M,256]); fpb = bf16(seq + ts).
// ---------------------------------------------------------------------------
__global__ __launch_bounds__(256)
void prep_kernel(const float* __restrict__ seq, const float* __restrict__ ts,
                 unsigned short* __restrict__ flatb, unsigned short* __restrict__ fpb) {
  const int row = blockIdx.x * 8 + (threadIdx.x >> 5);
  const int c0 = (threadIdx.x & 31) * 8;
  const int bn = row >> 8, s = row & 255;
  const int b = bn >> 5, n = bn & 31;
  const float* sp = &seq[((((b << 8) + s) << 5) + n) * 256 + c0];
  const float* tp = &ts[(((b << 8) + s) << 8) + c0];
  const float4 a0 = *(const float4*)sp, a1 = *(const float4*)(sp + 4);
  const float4 t0 = *(const float4*)tp, t1 = *(const float4*)(tp + 4);
  short8 fv, gv;
  fv[0] = (short)f2bf(a0.x); fv[1] = (short)f2bf(a0.y);
  fv[2] = (short)f2bf(a0.z); fv[3] = (short)f2bf(a0.w);
  fv[4] = (short)f2bf(a1.x); fv[5] = (short)f2bf(a1.y);
  fv[6] = (short)f2bf(a1.z); fv[7] = (short)f2bf(a1.w);
  gv[0] = (short)f2bf(a0.x + t0.x); gv[1] = (short)f2bf(a0.y + t0.y);
  gv[2] = (short)f2bf(a0.z + t0.z); gv[3] = (short)f2bf(a0.w + t0.w);
  gv[4] = (short)f2bf(a1.x + t1.x); gv[5] = (short)f2bf(a1.y + t1.y);
  gv[6] = (short)f2bf(a1.z + t1.z); gv[7] = (short)f2bf(a1.w + t1.w);
  *(short8*)&flatb[row * 256 + c0] = fv;
  *(short8*)&fpb[row * 256 + c0] = gv;
}

// ---------------------------------------------------------------------------
// bf16 MFMA GEMM: C[M,NOUT] = epilogue(A @ W + bias)
// AMODE: 0 = fp32 A[M,K] (padded LDS, reg staging);
//        3 = bf16 A[M,K] (linear LDS, global_load_lds direct staging)
// RESMODE: 0 none; 2 + resb (bf16 [M,NOUT])
// DUALB: bias for col<256, bias2 for col>=256. SCALEH: post_scale only col<256.
// ---------------------------------------------------------------------------
template<int AMODE, int RESMODE, bool GELU_, int K, int NOUT, bool OUTBF,
         bool DUALB, bool SCALEH>
__global__ __launch_bounds__(256)
void mmb_kernel(const void* __restrict__ Av, const unsigned short* __restrict__ Wt,
                const float* __restrict__ bias, const float* __restrict__ bias2,
                const unsigned short* __restrict__ resb,
                void* __restrict__ Cv, float post_scale) {
  constexpr int LDA = (AMODE == 3) ? 64 : 72;
  constexpr int LDB = (AMODE == 3) ? 64 : 72;
  __shared__ unsigned short As[128 * 72];
  __shared__ unsigned short Bs[128 * 72];
  const int tid = threadIdx.x;
  const int m0 = blockIdx.x * 128, n0 = blockIdx.y * 128;
  const int l = tid & 63, w = tid >> 6;
  const int wr = w >> 1, wc = w & 1;
  const int lr = l & 15, lg = l >> 4;
  f32x4 acc[4][4] = {};

  // per-lane global bases for direct staging (AMODE==3)
  const unsigned short* ga = nullptr;
  const unsigned short* gb = nullptr;
  if (AMODE == 3) {
    ga = (const unsigned short*)Av + (m0 + w * 32 + (l >> 3)) * K + (l & 7) * 8;
    gb = Wt + (n0 + w * 32 + (l >> 3)) * K + (l & 7) * 8;
  }

  for (int k0 = 0; k0 < K; k0 += 64) {
    if (AMODE == 3) {
      // direct global->LDS: 4 insts each for A and B per wave (8 rows/inst)
#pragma unroll
      for (int i = 0; i < 4; ++i) {
        gload16(ga + k0 + i * 8 * K, &As[(w * 32 + i * 8) * 64]);
        gload16(gb + k0 + i * 8 * K, &Bs[(w * 32 + i * 8) * 64]);
      }
    } else {
#pragma unroll
      for (int i = 0; i < 8; ++i) {
        const int seg = i * 256 + tid;
        const int r = seg >> 4, c4 = (seg & 15) * 4;
        const float4 a4 = *(const float4*)&((const float*)Av)[(m0 + r) * K + k0 + c4];
        short4v sv;
        sv[0] = (short)f2bf(a4.x); sv[1] = (short)f2bf(a4.y);
        sv[2] = (short)f2bf(a4.z); sv[3] = (short)f2bf(a4.w);
        *(short4v*)&As[r * LDA + c4] = sv;
      }
#pragma unroll
      for (int i = 0; i < 4; ++i) {
        const int seg = i * 256 + tid;
        const int n = seg >> 3, c8 = (seg & 7) * 8;
        const short8 v = *(const short8*)&Wt[(n0 + n) * K + k0 + c8];
        *(short8*)&Bs[n * LDB + c8] = v;
      }
    }
    __syncthreads();
#pragma unroll
    for (int ks = 0; ks < 2; ++ks) {
      short8 af[4], bfr[4];
#pragma unroll
      for (int qt = 0; qt < 4; ++qt)
        af[qt] = *(const short8*)&As[(wr * 64 + qt * 16 + lr) * LDA + ks * 32 + lg * 8];
#pragma unroll
      for (int nt = 0; nt < 4; ++nt)
        bfr[nt] = *(const short8*)&Bs[(wc * 64 + nt * 16 + lr) * LDB + ks * 32 + lg * 8];
#pragma unroll
      for (int qt = 0; qt < 4; ++qt)
#pragma unroll
        for (int nt = 0; nt < 4; ++nt)
          acc[qt][nt] = __builtin_amdgcn_mfma_f32_16x16x32_bf16(
              af[qt], bfr[nt], acc[qt][nt], 0, 0, 0);
    }
    __syncthreads();
  }

#pragma unroll
  for (int qt = 0; qt < 4; ++qt) {
#pragma unroll
    for (int nt = 0; nt < 4; ++nt) {
      const int col = n0 + wc * 64 + nt * 16 + lr;
      const float bsv = DUALB ? (col < 256 ? bias[col] : bias2[col - 256])
                              : bias[col];
      const float sc = SCALEH ? (col < 256 ? post_scale : 1.0f) : post_scale;
#pragma unroll
      for (int i = 0; i < 4; ++i) {
        const int row = m0 + wr * 64 + qt * 16 + (lg << 2) + i;
        float v = (acc[qt][nt][i] + bsv) * sc;
        if (RESMODE == 2) v += bf2f(resb[row * NOUT + col]);
        if (GELU_) v = 0.5f * v * (1.0f + erff(v * 0.70710678118654752f));
        if (OUTBF) ((unsigned short*)Cv)[row * NOUT + col] = f2bf(v);
        else       ((float*)Cv)[row * NOUT + col] = v;
      }
    }
  }
}

// ---------------------------------------------------------------------------
// Attention v7 = attn4 (round-6, best measured) + two changes:
//  (a) XCD-locality swizzle: bn = blockIdx&127, h = blockIdx>>7 -> the 8
//      h-blocks of one bn share blockIdx%8 -> same XCD -> staged qkb/vb
//      rows hit that XCD's L2 instead of being re-fetched by 8 XCDs.
//  (b) degenerate-row fallback DELETED: a valid query always has a valid
//      causal key (itself), so lrun==0 only for invalid queries, whose
//      rows are zeroed by LN2*valid downstream; our path yields finite 0s.
// 8 waves x 32 query rows; no-max softmax (scale folded into q/tq at GEMM);
// P exchange via __shfl_xor(.,32); direct global O stores. LDS 48KB.
// ---------------------------------------------------------------------------
__global__ __launch_bounds__(512, 4)
void attn4_kernel(const unsigned short* __restrict__ qkb,   // [M][512] q|k
                  const unsigned short* __restrict__ vb,    // [M][256]
                  const unsigned short* __restrict__ tqtkb, // [BS][512] tq|tk
                  const int* __restrict__ valid,
                  unsigned short* __restrict__ ao) {
  __shared__ __align__(16) char KsB[256 * 128];   // K' [key][d64], swizzled
  __shared__ __align__(16) char VsB[32 * 512];    // V^T [dv][key], swizzled

  const int bn = blockIdx.x & 127;      // XCD swizzle: same-bn blocks share
  const int h = blockIdx.x >> 7;        // blockIdx%8 -> same XCD L2
  const int b = bn >> 5, n = bn & 31;
  const int tid = threadIdx.x, l = tid & 63, w = tid >> 6;  // w = query chunk
  const int lq = l & 31, hi = l >> 5;
  const int qa = w * 32 + lq;          // this lane's query row

  const unsigned long long bm0 = __ballot(valid[((b << 8) + 0   + l) * 32 + n] != 0);
  const unsigned long long bm1 = __ballot(valid[((b << 8) + 64  + l) * 32 + n] != 0);
  const unsigned long long bm2 = __ballot(valid[((b << 8) + 128 + l) * 32 + n] != 0);
  const unsigned long long bm3 = __ballot(valid[((b << 8) + 192 + l) * 32 + n] != 0);

  // Q' fragments (B-operand): col = own q, k = 8*hi + j per 16-wide K chunk.
  // q columns pre-scaled by c2, tq by 0.25*c2 (folded at GEMM).
  short8 qf[4];
  {
    const unsigned short* qp = &qkb[((bn << 8) + qa) * 512 + (h << 5)];
    const unsigned short* tp = &tqtkb[((b << 8) + qa) * 512 + (h << 5)];
    qf[0] = *(const short8*)&qp[hi * 8];
    qf[1] = *(const short8*)&qp[16 + hi * 8];
    qf[2] = *(const short8*)&tp[hi * 8];
    qf[3] = *(const short8*)&tp[16 + hi * 8];
  }

  // stage K' (k | tk), swizzled: byte = key*128 + ((c*16) ^ ((key&7)<<4))
#pragma unroll
  for (int i = 0; i < 4; ++i) {
    const int e = i * 512 + tid;
    const int key = e >> 3, c = e & 7;
    const unsigned short* src = (c < 4)
        ? &qkb[((bn << 8) + key) * 512 + 256 + (h << 5) + c * 8]
        : &tqtkb[((b << 8) + key) * 512 + 256 + (h << 5) + (c - 4) * 8];
    *(short8*)(KsB + key * 128 + ((c * 16) ^ ((key & 7) << 4))) = *(const short8*)src;
  }
  // stage V^T, swizzled: byte = dv*512 + ((key*2) ^ ((dv&7)<<4))
#pragma unroll
  for (int i = 0; i < 2; ++i) {
    const int e = i * 512 + tid;
    const int key = e >> 2, c = e & 3;
    const short8 v = *(const short8*)&vb[((bn << 8) + key) * 256 + (h << 5) + c * 8];
#pragma unroll
    for (int j = 0; j < 8; ++j) {
      const int dv = c * 8 + j;
      *(unsigned short*)(VsB + dv * 512 + ((key * 2) ^ ((dv & 7) << 4))) =
          (unsigned short)v[j];
    }
  }
  __syncthreads();

  f32x16 oacc = {};
  float lrun = 0.0f;

  for (int g = 0; g <= w; ++g) {
    const int kbase = g << 5;
    // S^T = mfma(K'_tile, Q') -- already in log2 domain (scale folded)
    f32x16 s = {};
#pragma unroll
    for (int df = 0; df < 4; ++df) {
      const int key = kbase + lq;
      const short8 akf = *(const short8*)(
          KsB + key * 128 + ((df * 32 + hi * 16) ^ ((key & 7) << 4)));
      s = __builtin_amdgcn_mfma_f32_32x32x16_bf16(akf, qf[df], s, 0, 0, 0);
    }
    const unsigned long long bmc = (kbase < 64) ? bm0 : (kbase < 128) ? bm1
                                 : (kbase < 192) ? bm2 : bm3;
    const unsigned wnd = (kbase & 32) ? (unsigned)(bmc >> 32) : (unsigned)bmc;
    // p = masked ? 0 : exp2(s)   (no-max online softmax)
    float p[16];
#pragma unroll
    for (int r = 0; r < 16; ++r) {
      const int crow = (r & 3) + 8 * (r >> 2) + 4 * hi;
      const int key = kbase + crow;
      const bool ok = (key <= qa) && (((wnd >> crow) & 1u) != 0u);
      p[r] = ok ? __builtin_amdgcn_exp2f(s[r]) : 0.0f;
    }
    float rs = ((p[0] + p[1]) + (p[2] + p[3])) + ((p[4] + p[5]) + (p[6] + p[7]))
             + ((p[8] + p[9]) + (p[10] + p[11])) + ((p[12] + p[13]) + (p[14] + p[15]));
    rs += __shfl_xor(rs, 32);
    lrun += rs;
    // pack to bf16 pairs and exchange halves via shfl_xor(32)
    unsigned wds[8];
#pragma unroll
    for (int i2 = 0; i2 < 8; ++i2)
      wds[i2] = (unsigned)f2bf(p[2 * i2]) | ((unsigned)f2bf(p[2 * i2 + 1]) << 16);
    unsigned xw[8];
#pragma unroll
    for (int i2 = 0; i2 < 8; ++i2)
      xw[i2] = (unsigned)__shfl_xor((int)wds[i2], 32);
    // B-fragments: frag0 = keys kbase+hi*8+j, frag1 = keys kbase+16+hi*8+j
    i32x4 f0, f1;
    f0[0] = (int)(hi ? xw[2] : wds[0]);
    f0[1] = (int)(hi ? xw[3] : wds[1]);
    f0[2] = (int)(hi ? wds[2] : xw[0]);
    f0[3] = (int)(hi ? wds[3] : xw[1]);
    f1[0] = (int)(hi ? xw[6] : wds[4]);
    f1[1] = (int)(hi ? xw[7] : wds[5]);
    f1[2] = (int)(hi ? wds[6] : xw[4]);
    f1[3] = (int)(hi ? wds[7] : xw[5]);
    const short8 pf0 = __builtin_bit_cast(short8, f0);
    const short8 pf1 = __builtin_bit_cast(short8, f1);
    // PV: O^T += mfma(V^T, P)
    {
      const short8 avf = *(const short8*)(
          VsB + lq * 512 + (((kbase + hi * 8) * 2) ^ ((lq & 7) << 4)));
      oacc = __builtin_amdgcn_mfma_f32_32x32x16_bf16(avf, pf0, oacc, 0, 0, 0);
    }
    {
      const short8 avf = *(const short8*)(
          VsB + lq * 512 + (((kbase + 16 + hi * 8) * 2) ^ ((lq & 7) << 4)));
      oacc = __builtin_amdgcn_mfma_f32_32x32x16_bf16(avf, pf1, oacc, 0, 0, 0);
    }
  }

  // NOTE: no degenerate-row fallback needed. lrun==0 only for invalid query
  // rows (a valid query always has itself as a valid causal key); those rows
  // are zeroed by LN2*valid downstream, and this path stores finite 0s.

  // direct store: lane holds O^T[dv=crow(r,hi)][q=lq]; groups of 4 dv -> 8B
  const float inv = 1.0f / fmaxf(lrun, 1e-6f);
  const int row = (bn << 8) + qa;
#pragma unroll
  for (int g2 = 0; g2 < 4; ++g2) {
    const unsigned long long h0 = f2bf(oacc[4 * g2 + 0] * inv);
    const unsigned long long h1 = f2bf(oacc[4 * g2 + 1] * inv);
    const unsigned long long h2 = f2bf(oacc[4 * g2 + 2] * inv);
    const unsigned long long h3 = f2bf(oacc[4 * g2 + 3] * inv);
    const unsigned long long pkt = h0 | (h1 << 16) | (h2 << 32) | (h3 << 48);
    *(unsigned long long*)&ao[row * 256 + (h << 5) + 8 * g2 + 4 * hi] = pkt;
  }
}

// ---------------------------------------------------------------------------
// LN1: fp32 in -> bf16 out (flat). LN2: fp32 in -> fp32 out, *valid, scatter.
// ---------------------------------------------------------------------------
__global__ __launch_bounds__(256)
void ln1_kernel(const float* __restrict__ X, const float* __restrict__ g,
                const float* __restrict__ bb, unsigned short* __restrict__ out) {
  const int row = blockIdx.x * 4 + (threadIdx.x >> 6);
  const int lane = threadIdx.x & 63;
  const float4 x = *(const float4*)&X[row * 256 + lane * 4];
  float s1 = x.x + x.y + x.z + x.w;
#pragma unroll
  for (int off = 1; off < 64; off <<= 1) s1 += __shfl_xor(s1, off);
  const float mean = s1 * (1.0f / 256.0f);
  const float dx = x.x - mean, dy = x.y - mean, dz = x.z - mean, dw = x.w - mean;
  float s2 = dx * dx + dy * dy + dz * dz + dw * dw;
#pragma unroll
  for (int off = 1; off < 64; off <<= 1) s2 += __shfl_xor(s2, off);
  const float rstd = rsqrtf(s2 * (1.0f / 256.0f) + 1e-5f);
  const int c0 = lane * 4;
  short4v y;
  y[0] = (short)f2bf(dx * rstd * g[c0] + bb[c0]);
  y[1] = (short)f2bf(dy * rstd * g[c0 + 1] + bb[c0 + 1]);
  y[2] = (short)f2bf(dz * rstd * g[c0 + 2] + bb[c0 + 2]);
  y[3] = (short)f2bf(dw * rstd * g[c0 + 3] + bb[c0 + 3]);
  *(short4v*)&out[row * 256 + c0] = y;
}

__global__ __launch_bounds__(256)
void ln2_kernel(const float* __restrict__ X, const float* __restrict__ g,
                const float* __restrict__ bb, float* __restrict__ out,
                const int* __restrict__ valid) {
  const int row = blockIdx.x * 4 + (threadIdx.x >> 6);
  const int lane = threadIdx.x & 63;
  const float4 x = *(const float4*)&X[row * 256 + lane * 4];
  float s1 = x.x + x.y + x.z + x.w;
#pragma unroll
  for (int off = 1; off < 64; off <<= 1) s1 += __shfl_xor(s1, off);
  const float mean = s1 * (1.0f / 256.0f);
  const float dx = x.x - mean, dy = x.y - mean, dz = x.z - mean, dw = x.w - mean;
  float s2 = dx * dx + dy * dy + dz * dz + dw * dw;
#pragma unroll
  for (int off = 1; off < 64; off <<= 1) s2 += __shfl_xor(s2, off);
  const float rstd = rsqrtf(s2 * (1.0f / 256.0f) + 1e-5f);
  const int c0 = lane * 4;
  const int bn = row >> 8, s = row & 255;
  const int b = bn >> 5, n = bn & 31;
  const float vmv = (valid[((b << 8) + s) * 32 + n] != 0) ? 1.0f : 0.0f;
  float4 y;
  y.x = (dx * rstd * g[c0] + bb[c0]) * vmv;
  y.y = (dy * rstd * g[c0 + 1] + bb[c0 + 1]) * vmv;
  y.z = (dz * rstd * g[c0 + 2] + bb[c0 + 2]) * vmv;
  y.w = (dw * rstd * g[c0 + 3] + bb[c0 + 3]) * vmv;
  *(float4*)&out[(((((b << 8) + s) << 5) + n) << 8) + c0] = y;
}

// ---------------------------------------------------------------------------
extern "C" void kernel_launch(void* const* d_in, const int* in_sizes, int n_in,
                              void* d_out, int out_size, void* d_ws, size_t ws_size,
                              hipStream_t stream) {
  const float* seq    = (const float*)d_in[0];
  const float* regs   = (const float*)d_in[1];
  const float* trs    = (const float*)d_in[2];
  const float* q_w    = (const float*)d_in[3];
  const float* q_b    = (const float*)d_in[4];
  const float* k_w    = (const float*)d_in[5];
  const float* k_b    = (const float*)d_in[6];
  const float* v_w    = (const float*)d_in[7];
  const float* v_b    = (const float*)d_in[8];
  const float* o_w    = (const float*)d_in[9];
  const float* o_b    = (const float*)d_in[10];
  const float* semb   = (const float*)d_in[11];
  const float* reg_w  = (const float*)d_in[12];
  const float* reg_b  = (const float*)d_in[13];
  const float* tr_w   = (const float*)d_in[14];
  const float* tr_b   = (const float*)d_in[15];
  const float* tq_w   = (const float*)d_in[16];
  const float* tq_b   = (const float*)d_in[17];
  const float* tk_w   = (const float*)d_in[18];
  const float* tk_b   = (const float*)d_in[19];
  const float* ff_w1  = (const float*)d_in[20];
  const float* ff_b1  = (const float*)d_in[21];
  const float* ff_w2  = (const float*)d_in[22];
  const float* ff_b2  = (const float*)d_in[23];
  const float* ln1_g  = (const float*)d_in[24];
  const float* ln1_b  = (const float*)d_in[25];
  const float* ln2_g  = (const float*)d_in[26];
  const float* ln2_b  = (const float*)d_in[27];
  const int*   valid  = (const int*)d_in[28];
  const int*   codes  = (const int*)d_in[29];

  float* f32ws = (float*)d_ws;
  float* ts    = f32ws;                 // 262144 f
  float* x1pre = f32ws + 262144;        // 8388608 f (reused as x2)
  unsigned short* bws = (unsigned short*)(f32ws + 262144 + 8388608);
  unsigned short* flatb = bws;                    // 8388608  (x1b alias)
  unsigned short* fpb   = bws + 8388608;          // 8388608  (ao alias)
  unsigned short* qkb   = bws + 16777216;         // 16777216 (h1 alias)
  unsigned short* vb    = bws + 33554432;         // 8388608
  unsigned short* tqtkb = bws + 41943040;         // 524288
  unsigned short* wqk   = bws + 42467328;         // 131072
  unsigned short* wv    = bws + 42598400;         // 65536
  unsigned short* wo    = bws + 42663936;         // 65536
  unsigned short* wtqtk = bws + 42729472;         // 131072
  unsigned short* wff1  = bws + 42860544;         // 131072
  unsigned short* wff2  = bws + 42991616;         // 131072  (end 43122688)
  unsigned short* ao  = fpb;
  unsigned short* x1b = flatb;
  unsigned short* h1  = qkb;
  float* x2 = x1pre;
  float* outp = (float*)d_out;

  const float c2 = 0.25505402f;  // (1/sqrt(32)) * log2(e) -- folded into q/tq

  // 1. time state + weight conversion (independent)
  ts_kernel<<<BS_, 256, 0, stream>>>(regs, trs, codes, semb, reg_w, reg_b,
                                     tr_w, tr_b, ts);
  cvtall_kernel<<<2560, 256, 0, stream>>>(q_w, k_w, v_w, o_w, tq_w, tk_w,
                                          ff_w1, ff_w2, wqk, wv, wo, wtqtk,
                                          wff1, wff2);
  // 2. prep: flatb = bf16(flat), fpb = bf16(flat + ts)
  prep_kernel<<<M_ / 8, 256, 0, stream>>>(seq, ts, flatb, fpb);
  // 3. temporal projections merged (tq|tk); 0.25*c2 folded into tq half
  mmb_kernel<0, 0, false, 256, 512, true, true, true>
      <<<dim3(8, 4), 256, 0, stream>>>(ts, wtqtk, tq_b, tk_b, nullptr,
                                       tqtkb, 0.25f * c2);
  // 4. q|k merged projection (c2 folded into q half); v projection
  mmb_kernel<3, 0, false, 256, 512, true, true, true>
      <<<dim3(256, 4), 256, 0, stream>>>(fpb, wqk, q_b, k_b, nullptr,
                                         qkb, c2);
  mmb_kernel<3, 0, false, 256, 256, true, false, false>
      <<<dim3(256, 2), 256, 0, stream>>>(flatb, wv, v_b, nullptr, nullptr,
                                         vb, 1.0f);
  // 5. attention (v7: attn4 + XCD swizzle, no degenerate loop)
  attn4_kernel<<<BN_ * NH_, 512, 0, stream>>>(qkb, vb, tqtkb, valid, ao);
  // 6. o-proj + flat residual (bf16) -> x1pre (fp32); LN1 -> x1b (bf16)
  mmb_kernel<3, 2, false, 256, 256, false, false, false>
      <<<dim3(256, 2), 256, 0, stream>>>(ao, wo, o_b, nullptr, flatb,
                                         x1pre, 1.0f);
  ln1_kernel<<<M_ / 4, 256, 0, stream>>>(x1pre, ln1_g, ln1_b, x1b);
  // 7. FF
  mmb_kernel<3, 0, true, 256, 512, true, false, false>
      <<<dim3(256, 4), 256, 0, stream>>>(x1b, wff1, ff_b1, nullptr, nullptr,
                                         h1, 1.0f);
  mmb_kernel<3, 2, false, 512, 256, false, false, false>
      <<<dim3(256, 2), 256, 0, stream>>>(h1, wff2, ff_b2, nullptr, x1b,
                                         x2, 1.0f);
  // 8. LN2 * valid -> output layout
  ln2_kernel<<<M_ / 4, 256, 0, stream>>>(x2, ln2_g, ln2_b, outp, valid);
}

// Round 11
// 172.528 us; speedup vs baseline: 2.0805x; 1.1044x over previous
//
#include <hip/hip_runtime.h>
#include <math.h>

// Shapes (fixed)
#define B_ 4
#define S_ 256
#define N_ 32
#define H_ 256
#define NH_ 8
#define HD_ 32
#define FF_ 512
#define BN_ 128
#define M_ 32768   // BN_*S_
#define BS_ 1024   // B_*S_

typedef __attribute__((ext_vector_type(8))) short short8;
typedef __attribute__((ext_vector_type(4))) short short4v;
typedef __attribute__((ext_vector_type(4))) float f32x4;
typedef __attribute__((ext_vector_type(16))) float f32x16;
typedef __attribute__((ext_vector_type(4))) int i32x4;

__device__ __forceinline__ unsigned short f2bf(float f) {
  unsigned u = __builtin_bit_cast(unsigned, f);
  u = (u + 0x7FFFu + ((u >> 16) & 1u)) >> 16;
  return (unsigned short)u;
}
__device__ __forceinline__ float bf2f(unsigned short h) {
  unsigned u = ((unsigned)h) << 16;
  return __builtin_bit_cast(float, u);
}

// Direct global->LDS DMA, 16B per lane (lands at ldsbase + lane*16).
__device__ __forceinline__ void gload16(const void* g, void* l) {
  __builtin_amdgcn_global_load_lds(
      (const __attribute__((address_space(1))) unsigned*)g,
      (__attribute__((address_space(3))) unsigned*)l, 16, 0, 0);
}

// ---------------------------------------------------------------------------
// time_state[bs, h] (fp32)
// ---------------------------------------------------------------------------
__global__ __launch_bounds__(256)
void ts_kernel(const float* __restrict__ reg, const float* __restrict__ tr,
               const int* __restrict__ codes,
               const float* __restrict__ sess_emb,
               const float* __restrict__ reg_w, const float* __restrict__ reg_b,
               const float* __restrict__ tr_w, const float* __restrict__ tr_b,
               float* __restrict__ ts) {
  const int bs = blockIdx.x;
  const int h = threadIdx.x;
  int c = codes[bs];
  c = c < 0 ? 0 : (c > 7 ? 7 : c);
  const float r = reg[bs], t = tr[bs];
  ts[bs * H_ + h] = sess_emb[c * H_ + h] + r * reg_w[h] + reg_b[h]
                    + t * tr_w[h] + tr_b[h];
}

// ---------------------------------------------------------------------------
// All weight conversions in one launch. W[K][N] fp32 -> Wt[N][K] bf16.
// ---------------------------------------------------------------------------
__global__ __launch_bounds__(256)
void cvtall_kernel(const float* __restrict__ q_w, const float* __restrict__ k_w,
                   const float* __restrict__ v_w, const float* __restrict__ o_w,
                   const float* __restrict__ tq_w, const float* __restrict__ tk_w,
                   const float* __restrict__ ff1_w, const float* __restrict__ ff2_w,
                   unsigned short* __restrict__ wqk, unsigned short* __restrict__ wv,
                   unsigned short* __restrict__ wo, unsigned short* __restrict__ wtqtk,
                   unsigned short* __restrict__ wff1, unsigned short* __restrict__ wff2) {
  const int bid = blockIdx.x, tid = threadIdx.x;
  const float* src; unsigned short* dst; int ns, K, base;
  if (bid < 256)       { src = q_w;   dst = wqk;           ns = 8; K = 256; base = 0; }
  else if (bid < 512)  { src = k_w;   dst = wqk + 65536;   ns = 8; K = 256; base = 256; }
  else if (bid < 768)  { src = v_w;   dst = wv;            ns = 8; K = 256; base = 512; }
  else if (bid < 1024) { src = o_w;   dst = wo;            ns = 8; K = 256; base = 768; }
  else if (bid < 1280) { src = tq_w;  dst = wtqtk;         ns = 8; K = 256; base = 1024; }
  else if (bid < 1536) { src = tk_w;  dst = wtqtk + 65536; ns = 8; K = 256; base = 1280; }
  else if (bid < 2048) { src = ff1_w; dst = wff1;          ns = 9; K = 256; base = 1536; }
  else                 { src = ff2_w; dst = wff2;          ns = 8; K = 512; base = 2048; }
  const int idx = (bid - base) * 256 + tid;
  const int k = idx >> ns, n = idx & ((1 << ns) - 1);
  dst[n * K + k] = f2bf(src[idx]);
}

// ---------------------------------------------------------------------------
// Prep: flatb = bf16(seq gathered to [M,256]); fpb = bf16(seq + ts).
// ---------------------------------------------------------------------------
__global__ __launch_bounds__(256)
void prep_kernel(const float* __restrict__ seq, const float* __restrict__ ts,
                 unsigned short* __restrict__ flatb, unsigned short* __restrict__ fpb) {
  const int row = blockIdx.x * 8 + (threadIdx.x >> 5);
  const int c0 = (threadIdx.x & 31) * 8;
  const int bn = row >> 8, s = row & 255;
  const int b = bn >> 5, n = bn & 31;
  const float* sp = &seq[((((b << 8) + s) << 5) + n) * 256 + c0];
  const float* tp = &ts[(((b << 8) + s) << 8) + c0];
  const float4 a0 = *(const float4*)sp, a1 = *(const float4*)(sp + 4);
  const float4 t0 = *(const float4*)tp, t1 = *(const float4*)(tp + 4);
  short8 fv, gv;
  fv[0] = (short)f2bf(a0.x); fv[1] = (short)f2bf(a0.y);
  fv[2] = (short)f2bf(a0.z); fv[3] = (short)f2bf(a0.w);
  fv[4] = (short)f2bf(a1.x); fv[5] = (short)f2bf(a1.y);
  fv[6] = (short)f2bf(a1.z); fv[7] = (short)f2bf(a1.w);
  gv[0] = (short)f2bf(a0.x + t0.x); gv[1] = (short)f2bf(a0.y + t0.y);
  gv[2] = (short)f2bf(a0.z + t0.z); gv[3] = (short)f2bf(a0.w + t0.w);
  gv[4] = (short)f2bf(a1.x + t1.x); gv[5] = (short)f2bf(a1.y + t1.y);
  gv[6] = (short)f2bf(a1.z + t1.z); gv[7] = (short)f2bf(a1.w + t1.w);
  *(short8*)&flatb[row * 256 + c0] = fv;
  *(short8*)&fpb[row * 256 + c0] = gv;
}

// ---------------------------------------------------------------------------
// bf16 MFMA GEMM: C[M,NOUT] = epilogue(A @ W + bias)
// AMODE: 0 = fp32 A[M,K] (padded LDS, reg staging);
//        3 = bf16 A[M,K] (linear LDS, global_load_lds direct staging)
// RESMODE: 0 none; 2 + resb (bf16 [M,NOUT])
// DUALB: bias for col<256, bias2 for col>=256. SCALEH: post_scale only col<256.
// ---------------------------------------------------------------------------
template<int AMODE, int RESMODE, bool GELU_, int K, int NOUT, bool OUTBF,
         bool DUALB, bool SCALEH>
__global__ __launch_bounds__(256)
void mmb_kernel(const void* __restrict__ Av, const unsigned short* __restrict__ Wt,
                const float* __restrict__ bias, const float* __restrict__ bias2,
                const unsigned short* __restrict__ resb,
                void* __restrict__ Cv, float post_scale) {
  constexpr int LDA = (AMODE == 3) ? 64 : 72;
  constexpr int LDB = (AMODE == 3) ? 64 : 72;
  __shared__ unsigned short As[128 * 72];
  __shared__ unsigned short Bs[128 * 72];
  const int tid = threadIdx.x;
  const int m0 = blockIdx.x * 128, n0 = blockIdx.y * 128;
  const int l = tid & 63, w = tid >> 6;
  const int wr = w >> 1, wc = w & 1;
  const int lr = l & 15, lg = l >> 4;
  f32x4 acc[4][4] = {};

  // per-lane global bases for direct staging (AMODE==3)
  const unsigned short* ga = nullptr;
  const unsigned short* gb = nullptr;
  if (AMODE == 3) {
    ga = (const unsigned short*)Av + (m0 + w * 32 + (l >> 3)) * K + (l & 7) * 8;
    gb = Wt + (n0 + w * 32 + (l >> 3)) * K + (l & 7) * 8;
  }

  for (int k0 = 0; k0 < K; k0 += 64) {
    if (AMODE == 3) {
#pragma unroll
      for (int i = 0; i < 4; ++i) {
        gload16(ga + k0 + i * 8 * K, &As[(w * 32 + i * 8) * 64]);
        gload16(gb + k0 + i * 8 * K, &Bs[(w * 32 + i * 8) * 64]);
      }
    } else {
#pragma unroll
      for (int i = 0; i < 8; ++i) {
        const int seg = i * 256 + tid;
        const int r = seg >> 4, c4 = (seg & 15) * 4;
        const float4 a4 = *(const float4*)&((const float*)Av)[(m0 + r) * K + k0 + c4];
        short4v sv;
        sv[0] = (short)f2bf(a4.x); sv[1] = (short)f2bf(a4.y);
        sv[2] = (short)f2bf(a4.z); sv[3] = (short)f2bf(a4.w);
        *(short4v*)&As[r * LDA + c4] = sv;
      }
#pragma unroll
      for (int i = 0; i < 4; ++i) {
        const int seg = i * 256 + tid;
        const int n = seg >> 3, c8 = (seg & 7) * 8;
        const short8 v = *(const short8*)&Wt[(n0 + n) * K + k0 + c8];
        *(short8*)&Bs[n * LDB + c8] = v;
      }
    }
    __syncthreads();
#pragma unroll
    for (int ks = 0; ks < 2; ++ks) {
      short8 af[4], bfr[4];
#pragma unroll
      for (int qt = 0; qt < 4; ++qt)
        af[qt] = *(const short8*)&As[(wr * 64 + qt * 16 + lr) * LDA + ks * 32 + lg * 8];
#pragma unroll
      for (int nt = 0; nt < 4; ++nt)
        bfr[nt] = *(const short8*)&Bs[(wc * 64 + nt * 16 + lr) * LDB + ks * 32 + lg * 8];
#pragma unroll
      for (int qt = 0; qt < 4; ++qt)
#pragma unroll
        for (int nt = 0; nt < 4; ++nt)
          acc[qt][nt] = __builtin_amdgcn_mfma_f32_16x16x32_bf16(
              af[qt], bfr[nt], acc[qt][nt], 0, 0, 0);
    }
    __syncthreads();
  }

#pragma unroll
  for (int qt = 0; qt < 4; ++qt) {
#pragma unroll
    for (int nt = 0; nt < 4; ++nt) {
      const int col = n0 + wc * 64 + nt * 16 + lr;
      const float bsv = DUALB ? (col < 256 ? bias[col] : bias2[col - 256])
                              : bias[col];
      const float sc = SCALEH ? (col < 256 ? post_scale : 1.0f) : post_scale;
#pragma unroll
      for (int i = 0; i < 4; ++i) {
        const int row = m0 + wr * 64 + qt * 16 + (lg << 2) + i;
        float v = (acc[qt][nt][i] + bsv) * sc;
        if (RESMODE == 2) v += bf2f(resb[row * NOUT + col]);
        if (GELU_) v = 0.5f * v * (1.0f + erff(v * 0.70710678118654752f));
        if (OUTBF) ((unsigned short*)Cv)[row * NOUT + col] = f2bf(v);
        else       ((float*)Cv)[row * NOUT + col] = v;
      }
    }
  }
}

// ---------------------------------------------------------------------------
// Fused GEMM (NOUT=256, full row per block) + residual + LayerNorm.
// Tile 64 rows x 256 cols, 4 waves (wave = 64-col quarter), acc[4][4].
// A/B staged via global_load_lds (linear LDS, m97 structure).
// Row mean/var: in-wave shfl over lr + 4-way cross-wave LDS combine.
// FINAL=false: write bf16 [M][256] (LN1 path, out = x1b).
// FINAL=true:  write fp32, *valid, scatter to [B,S,N,H] (LN2 path, out=d_out).
// ---------------------------------------------------------------------------
template<int K, bool FINAL>
__global__ __launch_bounds__(256, 2)
void gemmln_kernel(const unsigned short* __restrict__ Ab,   // [M][K] bf16
                   const unsigned short* __restrict__ Wt,   // [256][K] bf16
                   const float* __restrict__ bias,
                   const unsigned short* __restrict__ resb, // [M][256] bf16
                   const float* __restrict__ g, const float* __restrict__ bb,
                   const int* __restrict__ valid,
                   void* __restrict__ out) {
  __shared__ unsigned short As[64 * 64];    // 8 KB
  __shared__ unsigned short Bs[256 * 64];   // 32 KB
  __shared__ float Red[4][64][2];           // 2 KB
  const int tid = threadIdx.x;
  const int m0 = blockIdx.x * 64;
  const int l = tid & 63, w = tid >> 6;     // w = col quarter
  const int lr = l & 15, lg = l >> 4;
  f32x4 acc[4][4] = {};

  const unsigned short* ga = Ab + (m0 + w * 16 + (l >> 3)) * K + (l & 7) * 8;
  const unsigned short* gb = Wt + (w * 64 + (l >> 3)) * K + (l & 7) * 8;

  for (int k0 = 0; k0 < K; k0 += 64) {
#pragma unroll
    for (int i = 0; i < 2; ++i)
      gload16(ga + k0 + i * 8 * K, &As[(w * 16 + i * 8) * 64]);
#pragma unroll
    for (int i = 0; i < 8; ++i)
      gload16(gb + k0 + i * 8 * K, &Bs[(w * 64 + i * 8) * 64]);
    __syncthreads();
#pragma unroll
    for (int ks = 0; ks < 2; ++ks) {
      short8 af[4], bfr[4];
#pragma unroll
      for (int qt = 0; qt < 4; ++qt)
        af[qt] = *(const short8*)&As[(qt * 16 + lr) * 64 + ks * 32 + lg * 8];
#pragma unroll
      for (int nt = 0; nt < 4; ++nt)
        bfr[nt] = *(const short8*)&Bs[(w * 64 + nt * 16 + lr) * 64 + ks * 32 + lg * 8];
#pragma unroll
      for (int qt = 0; qt < 4; ++qt)
#pragma unroll
        for (int nt = 0; nt < 4; ++nt)
          acc[qt][nt] = __builtin_amdgcn_mfma_f32_16x16x32_bf16(
              af[qt], bfr[nt], acc[qt][nt], 0, 0, 0);
    }
    __syncthreads();
  }

  // Phase A: x = acc + bias + residual; per-row partial sums -> Red[w]
#pragma unroll
  for (int qt = 0; qt < 4; ++qt) {
#pragma unroll
    for (int i = 0; i < 4; ++i) {
      const int rl = qt * 16 + (lg << 2) + i;
      const int row = m0 + rl;
      float s1 = 0.0f, s2 = 0.0f;
#pragma unroll
      for (int nt = 0; nt < 4; ++nt) {
        const int col = w * 64 + nt * 16 + lr;
        float v = acc[qt][nt][i] + bias[col] + bf2f(resb[row * 256 + col]);
        acc[qt][nt][i] = v;
        s1 += v; s2 += v * v;
      }
      s1 += __shfl_xor(s1, 1); s2 += __shfl_xor(s2, 1);
      s1 += __shfl_xor(s1, 2); s2 += __shfl_xor(s2, 2);
      s1 += __shfl_xor(s1, 4); s2 += __shfl_xor(s2, 4);
      s1 += __shfl_xor(s1, 8); s2 += __shfl_xor(s2, 8);
      if (lr == 0) { Red[w][rl][0] = s1; Red[w][rl][1] = s2; }
    }
  }
  __syncthreads();

  // Phase B: combine 4 quarters, normalize, write own cols
#pragma unroll
  for (int qt = 0; qt < 4; ++qt) {
#pragma unroll
    for (int i = 0; i < 4; ++i) {
      const int rl = qt * 16 + (lg << 2) + i;
      const int row = m0 + rl;
      const float s1 = (Red[0][rl][0] + Red[1][rl][0])
                     + (Red[2][rl][0] + Red[3][rl][0]);
      const float s2 = (Red[0][rl][1] + Red[1][rl][1])
                     + (Red[2][rl][1] + Red[3][rl][1]);
      const float mean = s1 * (1.0f / 256.0f);
      const float var = s2 * (1.0f / 256.0f) - mean * mean;
      const float rstd = rsqrtf(var + 1e-5f);
      if (FINAL) {
        const int bn = row >> 8, s = row & 255;
        const int b = bn >> 5, n = bn & 31;
        const float vm = (valid[((b << 8) + s) * 32 + n] != 0) ? 1.0f : 0.0f;
        float* op = (float*)out + ((((b << 8) + s) << 5) + n) * 256;
#pragma unroll
        for (int nt = 0; nt < 4; ++nt) {
          const int col = w * 64 + nt * 16 + lr;
          op[col] = ((acc[qt][nt][i] - mean) * rstd * g[col] + bb[col]) * vm;
        }
      } else {
        unsigned short* op = (unsigned short*)out + row * 256;
#pragma unroll
        for (int nt = 0; nt < 4; ++nt) {
          const int col = w * 64 + nt * 16 + lr;
          op[col] = f2bf((acc[qt][nt][i] - mean) * rstd * g[col] + bb[col]);
        }
      }
    }
  }
}

// ---------------------------------------------------------------------------
// Attention v7 (round-9, best measured): XCD-locality swizzle
// (bn = blockIdx&127, h = blockIdx>>7), no-max softmax (scale folded into
// q/tq at GEMM), shfl_xor(32) P exchange, direct global O stores, no
// degenerate-row loop (invalid rows are zeroed by LN2*valid downstream).
// ---------------------------------------------------------------------------
__global__ __launch_bounds__(512, 4)
void attn4_kernel(const unsigned short* __restrict__ qkb,   // [M][512] q|k
                  const unsigned short* __restrict__ vb,    // [M][256]
                  const unsigned short* __restrict__ tqtkb, // [BS][512] tq|tk
                  const int* __restrict__ valid,
                  unsigned short* __restrict__ ao) {
  __shared__ __align__(16) char KsB[256 * 128];   // K' [key][d64], swizzled
  __shared__ __align__(16) char VsB[32 * 512];    // V^T [dv][key], swizzled

  const int bn = blockIdx.x & 127;      // XCD swizzle
  const int h = blockIdx.x >> 7;
  const int b = bn >> 5, n = bn & 31;
  const int tid = threadIdx.x, l = tid & 63, w = tid >> 6;  // w = query chunk
  const int lq = l & 31, hi = l >> 5;
  const int qa = w * 32 + lq;          // this lane's query row

  const unsigned long long bm0 = __ballot(valid[((b << 8) + 0   + l) * 32 + n] != 0);
  const unsigned long long bm1 = __ballot(valid[((b << 8) + 64  + l) * 32 + n] != 0);
  const unsigned long long bm2 = __ballot(valid[((b << 8) + 128 + l) * 32 + n] != 0);
  const unsigned long long bm3 = __ballot(valid[((b << 8) + 192 + l) * 32 + n] != 0);

  short8 qf[4];
  {
    const unsigned short* qp = &qkb[((bn << 8) + qa) * 512 + (h << 5)];
    const unsigned short* tp = &tqtkb[((b << 8) + qa) * 512 + (h << 5)];
    qf[0] = *(const short8*)&qp[hi * 8];
    qf[1] = *(const short8*)&qp[16 + hi * 8];
    qf[2] = *(const short8*)&tp[hi * 8];
    qf[3] = *(const short8*)&tp[16 + hi * 8];
  }

  // stage K' (k | tk), swizzled: byte = key*128 + ((c*16) ^ ((key&7)<<4))
#pragma unroll
  for (int i = 0; i < 4; ++i) {
    const int e = i * 512 + tid;
    const int key = e >> 3, c = e & 7;
    const unsigned short* src = (c < 4)
        ? &qkb[((bn << 8) + key) * 512 + 256 + (h << 5) + c * 8]
        : &tqtkb[((b << 8) + key) * 512 + 256 + (h << 5) + (c - 4) * 8];
    *(short8*)(KsB + key * 128 + ((c * 16) ^ ((key & 7) << 4))) = *(const short8*)src;
  }
  // stage V^T, swizzled: byte = dv*512 + ((key*2) ^ ((dv&7)<<4))
#pragma unroll
  for (int i = 0; i < 2; ++i) {
    const int e = i * 512 + tid;
    const int key = e >> 2, c = e & 3;
    const short8 v = *(const short8*)&vb[((bn << 8) + key) * 256 + (h << 5) + c * 8];
#pragma unroll
    for (int j = 0; j < 8; ++j) {
      const int dv = c * 8 + j;
      *(unsigned short*)(VsB + dv * 512 + ((key * 2) ^ ((dv & 7) << 4))) =
          (unsigned short)v[j];
    }
  }
  __syncthreads();

  f32x16 oacc = {};
  float lrun = 0.0f;

  for (int g = 0; g <= w; ++g) {
    const int kbase = g << 5;
    f32x16 s = {};
#pragma unroll
    for (int df = 0; df < 4; ++df) {
      const int key = kbase + lq;
      const short8 akf = *(const short8*)(
          KsB + key * 128 + ((df * 32 + hi * 16) ^ ((key & 7) << 4)));
      s = __builtin_amdgcn_mfma_f32_32x32x16_bf16(akf, qf[df], s, 0, 0, 0);
    }
    const unsigned long long bmc = (kbase < 64) ? bm0 : (kbase < 128) ? bm1
                                 : (kbase < 192) ? bm2 : bm3;
    const unsigned wnd = (kbase & 32) ? (unsigned)(bmc >> 32) : (unsigned)bmc;
    float p[16];
#pragma unroll
    for (int r = 0; r < 16; ++r) {
      const int crow = (r & 3) + 8 * (r >> 2) + 4 * hi;
      const int key = kbase + crow;
      const bool ok = (key <= qa) && (((wnd >> crow) & 1u) != 0u);
      p[r] = ok ? __builtin_amdgcn_exp2f(s[r]) : 0.0f;
    }
    float rs = ((p[0] + p[1]) + (p[2] + p[3])) + ((p[4] + p[5]) + (p[6] + p[7]))
             + ((p[8] + p[9]) + (p[10] + p[11])) + ((p[12] + p[13]) + (p[14] + p[15]));
    rs += __shfl_xor(rs, 32);
    lrun += rs;
    unsigned wds[8];
#pragma unroll
    for (int i2 = 0; i2 < 8; ++i2)
      wds[i2] = (unsigned)f2bf(p[2 * i2]) | ((unsigned)f2bf(p[2 * i2 + 1]) << 16);
    unsigned xw[8];
#pragma unroll
    for (int i2 = 0; i2 < 8; ++i2)
      xw[i2] = (unsigned)__shfl_xor((int)wds[i2], 32);
    i32x4 f0, f1;
    f0[0] = (int)(hi ? xw[2] : wds[0]);
    f0[1] = (int)(hi ? xw[3] : wds[1]);
    f0[2] = (int)(hi ? wds[2] : xw[0]);
    f0[3] = (int)(hi ? wds[3] : xw[1]);
    f1[0] = (int)(hi ? xw[6] : wds[4]);
    f1[1] = (int)(hi ? xw[7] : wds[5]);
    f1[2] = (int)(hi ? wds[6] : xw[4]);
    f1[3] = (int)(hi ? wds[7] : xw[5]);
    const short8 pf0 = __builtin_bit_cast(short8, f0);
    const short8 pf1 = __builtin_bit_cast(short8, f1);
    {
      const short8 avf = *(const short8*)(
          VsB + lq * 512 + (((kbase + hi * 8) * 2) ^ ((lq & 7) << 4)));
      oacc = __builtin_amdgcn_mfma_f32_32x32x16_bf16(avf, pf0, oacc, 0, 0, 0);
    }
    {
      const short8 avf = *(const short8*)(
          VsB + lq * 512 + (((kbase + 16 + hi * 8) * 2) ^ ((lq & 7) << 4)));
      oacc = __builtin_amdgcn_mfma_f32_32x32x16_bf16(avf, pf1, oacc, 0, 0, 0);
    }
  }

  const float inv = 1.0f / fmaxf(lrun, 1e-6f);
  const int row = (bn << 8) + qa;
#pragma unroll
  for (int g2 = 0; g2 < 4; ++g2) {
    const unsigned long long h0 = f2bf(oacc[4 * g2 + 0] * inv);
    const unsigned long long h1 = f2bf(oacc[4 * g2 + 1] * inv);
    const unsigned long long h2 = f2bf(oacc[4 * g2 + 2] * inv);
    const unsigned long long h3 = f2bf(oacc[4 * g2 + 3] * inv);
    const unsigned long long pkt = h0 | (h1 << 16) | (h2 << 32) | (h3 << 48);
    *(unsigned long long*)&ao[row * 256 + (h << 5) + 8 * g2 + 4 * hi] = pkt;
  }
}

// ---------------------------------------------------------------------------
extern "C" void kernel_launch(void* const* d_in, const int* in_sizes, int n_in,
                              void* d_out, int out_size, void* d_ws, size_t ws_size,
                              hipStream_t stream) {
  const float* seq    = (const float*)d_in[0];
  const float* regs   = (const float*)d_in[1];
  const float* trs    = (const float*)d_in[2];
  const float* q_w    = (const float*)d_in[3];
  const float* q_b    = (const float*)d_in[4];
  const float* k_w    = (const float*)d_in[5];
  const float* k_b    = (const float*)d_in[6];
  const float* v_w    = (const float*)d_in[7];
  const float* v_b    = (const float*)d_in[8];
  const float* o_w    = (const float*)d_in[9];
  const float* o_b    = (const float*)d_in[10];
  const float* semb   = (const float*)d_in[11];
  const float* reg_w  = (const float*)d_in[12];
  const float* reg_b  = (const float*)d_in[13];
  const float* tr_w   = (const float*)d_in[14];
  const float* tr_b   = (const float*)d_in[15];
  const float* tq_w   = (const float*)d_in[16];
  const float* tq_b   = (const float*)d_in[17];
  const float* tk_w   = (const float*)d_in[18];
  const float* tk_b   = (const float*)d_in[19];
  const float* ff_w1  = (const float*)d_in[20];
  const float* ff_b1  = (const float*)d_in[21];
  const float* ff_w2  = (const float*)d_in[22];
  const float* ff_b2  = (const float*)d_in[23];
  const float* ln1_g  = (const float*)d_in[24];
  const float* ln1_b  = (const float*)d_in[25];
  const float* ln2_g  = (const float*)d_in[26];
  const float* ln2_b  = (const float*)d_in[27];
  const int*   valid  = (const int*)d_in[28];
  const int*   codes  = (const int*)d_in[29];

  float* f32ws = (float*)d_ws;
  float* ts    = f32ws;                 // 262144 f
  unsigned short* bws = (unsigned short*)(f32ws + 262144 + 8388608);
  unsigned short* flatb = bws;                    // 8388608  (x1b alias)
  unsigned short* fpb   = bws + 8388608;          // 8388608  (ao alias)
  unsigned short* qkb   = bws + 16777216;         // 16777216 (h1 alias)
  unsigned short* vb    = bws + 33554432;         // 8388608
  unsigned short* tqtkb = bws + 41943040;         // 524288
  unsigned short* wqk   = bws + 42467328;         // 131072
  unsigned short* wv    = bws + 42598400;         // 65536
  unsigned short* wo    = bws + 42663936;         // 65536
  unsigned short* wtqtk = bws + 42729472;         // 131072
  unsigned short* wff1  = bws + 42860544;         // 131072
  unsigned short* wff2  = bws + 42991616;         // 131072  (end 43122688)
  unsigned short* ao  = fpb;
  unsigned short* x1b = flatb;    // oln reads flatb (phase A) then writes x1b
  unsigned short* h1  = qkb;      // (same rows, post-barrier) -- safe aliasing
  float* outp = (float*)d_out;

  const float c2 = 0.25505402f;  // (1/sqrt(32)) * log2(e) -- folded into q/tq

  // 1. time state + weight conversion
  ts_kernel<<<BS_, 256, 0, stream>>>(regs, trs, codes, semb, reg_w, reg_b,
                                     tr_w, tr_b, ts);
  cvtall_kernel<<<2560, 256, 0, stream>>>(q_w, k_w, v_w, o_w, tq_w, tk_w,
                                          ff_w1, ff_w2, wqk, wv, wo, wtqtk,
                                          wff1, wff2);
  // 2. prep: flatb = bf16(flat), fpb = bf16(flat + ts)
  prep_kernel<<<M_ / 8, 256, 0, stream>>>(seq, ts, flatb, fpb);
  // 3. temporal projections merged (tq|tk); 0.25*c2 folded into tq half
  mmb_kernel<0, 0, false, 256, 512, true, true, true>
      <<<dim3(8, 4), 256, 0, stream>>>(ts, wtqtk, tq_b, tk_b, nullptr,
                                       tqtkb, 0.25f * c2);
  // 4. q|k merged projection (c2 folded into q half); v projection
  mmb_kernel<3, 0, false, 256, 512, true, true, true>
      <<<dim3(256, 4), 256, 0, stream>>>(fpb, wqk, q_b, k_b, nullptr,
                                         qkb, c2);
  mmb_kernel<3, 0, false, 256, 256, true, false, false>
      <<<dim3(256, 2), 256, 0, stream>>>(flatb, wv, v_b, nullptr, nullptr,
                                         vb, 1.0f);
  // 5. attention
  attn4_kernel<<<BN_ * NH_, 512, 0, stream>>>(qkb, vb, tqtkb, valid, ao);
  // 6. FUSED o-proj + flat residual + LN1 -> x1b (bf16)
  gemmln_kernel<256, false><<<M_ / 64, 256, 0, stream>>>(
      ao, wo, o_b, flatb, ln1_g, ln1_b, nullptr, x1b);
  // 7. FF1 (GELU)
  mmb_kernel<3, 0, true, 256, 512, true, false, false>
      <<<dim3(256, 4), 256, 0, stream>>>(x1b, wff1, ff_b1, nullptr, nullptr,
                                         h1, 1.0f);
  // 8. FUSED ff2 + x1 residual + LN2 + valid + scatter -> out
  gemmln_kernel<512, true><<<M_ / 64, 256, 0, stream>>>(
      h1, wff2, ff_b2, x1b, ln2_g, ln2_b, valid, outp);
}